// Round 2
// baseline (3761.111 us; speedup 1.0000x reference)
//
#include <hip/hip_runtime.h>
#include <hip/hip_bf16.h>
#include <math.h>

// ---- problem constants ----
#define V_    50280
#define D_    768
#define NL_   8
#define DI_   1536
#define DS_   16
#define DC_   4
#define DTR_  48
#define NC_   4
#define B_    2
#define L_    1024
#define BL_   (B_*L_)        // 2048
#define E2_   (2*DI_)        // 3072
#define DBC_  (DTR_+2*DS_)   // 80
#define EPS_  1e-5f
#define NCH_  32             // scan chunks
#define CL_   32             // chunk length (NCH_*CL_ == L_)

// ============================================================
// embedding gather: x[b,l,:] = embed[ids[b,l],:]
// ============================================================
__global__ void k_embed(const int* __restrict__ ids, const float* __restrict__ embed,
                        float* __restrict__ x) {
    int idx = blockIdx.x * 256 + threadIdx.x;        // over BL_*D_/4
    int row = idx / (D_/4);
    int col = (idx % (D_/4)) * 4;
    int id  = ids[row];
    float4 v = *reinterpret_cast<const float4*>(embed + (size_t)id * D_ + col);
    *reinterpret_cast<float4*>(x + (size_t)row * D_ + col) = v;
}

// ============================================================
// rmsnorm per row (D_=768). block = 192 threads (3 waves), one row/block
// ============================================================
__global__ void k_rmsnorm(const float* __restrict__ in, const float* __restrict__ w,
                          float* __restrict__ out) {
    int row = blockIdx.x;
    int t   = threadIdx.x;                     // 0..191
    float4 v = *reinterpret_cast<const float4*>(in + (size_t)row * D_ + t * 4);
    float ss = v.x*v.x + v.y*v.y + v.z*v.z + v.w*v.w;
    #pragma unroll
    for (int o = 32; o > 0; o >>= 1) ss += __shfl_down(ss, o);
    __shared__ float red[3];
    if ((t & 63) == 0) red[t >> 6] = ss;
    __syncthreads();
    float tot = red[0] + red[1] + red[2];
    float scale = rsqrtf(tot * (1.0f / D_) + EPS_);
    float4 wv = *reinterpret_cast<const float4*>(w + t * 4);
    float4 o4 = make_float4(v.x*scale*wv.x, v.y*scale*wv.y, v.z*scale*wv.z, v.w*scale*wv.w);
    *reinterpret_cast<float4*>(out + (size_t)row * D_ + t * 4) = o4;
}

// ============================================================
// generic fp32 NT GEMM: C[M,N] = A[M,K] * B[N,K]^T  (+ epilogue)
// 256 threads as 16x16 grid; thread tile TM x TN; BM=16*TM, BN=16*TN
// TM % 4 == 0; TN == 2 or TN % 4 == 0 (vectorized LDS fragment loads)
// EPI: 0 = store, 1 = softplus(acc + bias[n]), 2 = C += acc
// ============================================================
template<int TM, int TN, int BK, int EPI>
__global__ __launch_bounds__(256) void k_gemm_nt(
        const float* __restrict__ A, const float* __restrict__ B,
        float* __restrict__ C, const float* __restrict__ bias,
        int M, int N, int K, int lda, int ldb, int ldc) {
    constexpr int BM = 16 * TM, BN = 16 * TN;
    __shared__ float As[BK][BM + 4];   // +4 floats: keeps rows 16B-aligned, kills write conflicts
    __shared__ float Bs[BK][BN + 4];
    int tid = threadIdx.x;
    int tx = tid & 15, ty = tid >> 4;
    int m0 = blockIdx.y * BM, n0 = blockIdx.x * BN;
    float acc[TM][TN] = {};

    for (int k0 = 0; k0 < K; k0 += BK) {
        // stage A tile (transposed into LDS)
        #pragma unroll
        for (int i4 = tid; i4 < BM * BK / 4; i4 += 256) {
            int m  = i4 / (BK / 4);
            int kk = (i4 % (BK / 4)) * 4;
            float4 v = make_float4(0.f, 0.f, 0.f, 0.f);
            if (m0 + m < M) {
                if (k0 + kk + 3 < K) {
                    v = *reinterpret_cast<const float4*>(A + (size_t)(m0 + m) * lda + k0 + kk);
                } else {
                    float tmp[4] = {0.f, 0.f, 0.f, 0.f};
                    for (int j = 0; j < 4; j++)
                        if (k0 + kk + j < K) tmp[j] = A[(size_t)(m0 + m) * lda + k0 + kk + j];
                    v = make_float4(tmp[0], tmp[1], tmp[2], tmp[3]);
                }
            }
            As[kk + 0][m] = v.x; As[kk + 1][m] = v.y; As[kk + 2][m] = v.z; As[kk + 3][m] = v.w;
        }
        // stage B tile
        #pragma unroll
        for (int i4 = tid; i4 < BN * BK / 4; i4 += 256) {
            int n  = i4 / (BK / 4);
            int kk = (i4 % (BK / 4)) * 4;
            float4 v = make_float4(0.f, 0.f, 0.f, 0.f);
            if (n0 + n < N) {
                if (k0 + kk + 3 < K) {
                    v = *reinterpret_cast<const float4*>(B + (size_t)(n0 + n) * ldb + k0 + kk);
                } else {
                    float tmp[4] = {0.f, 0.f, 0.f, 0.f};
                    for (int j = 0; j < 4; j++)
                        if (k0 + kk + j < K) tmp[j] = B[(size_t)(n0 + n) * ldb + k0 + kk + j];
                    v = make_float4(tmp[0], tmp[1], tmp[2], tmp[3]);
                }
            }
            Bs[kk + 0][n] = v.x; Bs[kk + 1][n] = v.y; Bs[kk + 2][n] = v.z; Bs[kk + 3][n] = v.w;
        }
        __syncthreads();
        #pragma unroll
        for (int kk = 0; kk < BK; kk++) {
            float a[TM], b[TN];
            #pragma unroll
            for (int i = 0; i < TM; i += 4) {          // ds_read_b128
                float4 v = *reinterpret_cast<const float4*>(&As[kk][ty * TM + i]);
                a[i] = v.x; a[i + 1] = v.y; a[i + 2] = v.z; a[i + 3] = v.w;
            }
            if constexpr (TN % 4 == 0) {
                #pragma unroll
                for (int j = 0; j < TN; j += 4) {      // ds_read_b128
                    float4 v = *reinterpret_cast<const float4*>(&Bs[kk][tx * TN + j]);
                    b[j] = v.x; b[j + 1] = v.y; b[j + 2] = v.z; b[j + 3] = v.w;
                }
            } else {                                   // TN == 2: ds_read_b64
                float2 v = *reinterpret_cast<const float2*>(&Bs[kk][tx * TN]);
                b[0] = v.x; b[1] = v.y;
            }
            #pragma unroll
            for (int i = 0; i < TM; i++)
                #pragma unroll
                for (int j = 0; j < TN; j++)
                    acc[i][j] += a[i] * b[j];
        }
        __syncthreads();
    }

    #pragma unroll
    for (int i = 0; i < TM; i++) {
        int m = m0 + ty * TM + i;
        if (m >= M) continue;
        #pragma unroll
        for (int j = 0; j < TN; j++) {
            int n = n0 + tx * TN + j;
            if (n >= N) continue;
            float v = acc[i][j];
            if (EPI == 1) {
                v += bias[n];
                v = (v > 20.f) ? v : log1pf(expf(v));
                C[(size_t)m * ldc + n] = v;
            } else if (EPI == 2) {
                C[(size_t)m * ldc + n] += v;
            } else {
                C[(size_t)m * ldc + n] = v;
            }
        }
    }
}

// ============================================================
// causal depthwise conv (DC=4) + silu.  x_in = xz[...,:DI]
// ============================================================
__global__ void k_conv_silu(const float* __restrict__ xz, const float* __restrict__ cw,
                            const float* __restrict__ cb, float* __restrict__ xc) {
    int bl = blockIdx.x / (DI_ / 256);
    int ig = blockIdx.x % (DI_ / 256);
    int i  = ig * 256 + threadIdx.x;
    int b  = bl / L_, l = bl % L_;
    float4 w4 = *reinterpret_cast<const float4*>(cw + (size_t)i * DC_);
    float acc = cb[i];
    const float wk[4] = {w4.x, w4.y, w4.z, w4.w};
    #pragma unroll
    for (int k = 0; k < DC_; k++) {
        int pos = l - (DC_ - 1) + k;
        float xv = (pos >= 0) ? xz[(size_t)(b * L_ + pos) * E2_ + i] : 0.f;
        acc += xv * wk[k];
    }
    float sig = 1.f / (1.f + __expf(-acc));
    xc[(size_t)bl * DI_ + i] = acc * sig;
}

// ============================================================
// scan pass 1: per-chunk local recurrence from h=0; store final state + sum(dt)
// grid (DI_/256, B_, NCH_)
// ============================================================
__global__ __launch_bounds__(256) void k_scan1(
        const float* __restrict__ dt, const float* __restrict__ xc,
        const float* __restrict__ dbc, const float* __restrict__ A_log,
        float* __restrict__ hL, float* __restrict__ sdt) {
    int i = blockIdx.x * 256 + threadIdx.x;
    int b = blockIdx.y, c = blockIdx.z;
    __shared__ float Bsh[CL_][DS_];
    for (int t = threadIdx.x; t < CL_ * DS_; t += 256) {
        int l = t / DS_, s = t % DS_;
        Bsh[l][s] = dbc[(size_t)(b * L_ + c * CL_ + l) * DBC_ + DTR_ + s];
    }
    __syncthreads();
    float a[DS_];
    #pragma unroll
    for (int s = 0; s < DS_; s++) a[s] = -__expf(A_log[(size_t)i * DS_ + s]);
    float h[DS_] = {};
    float sd = 0.f;
    const float* dtp = dt + (size_t)(b * L_ + c * CL_) * DI_ + i;
    const float* xcp = xc + (size_t)(b * L_ + c * CL_) * DI_ + i;
    for (int l = 0; l < CL_; l++) {
        float dv = dtp[(size_t)l * DI_];
        float xv = xcp[(size_t)l * DI_];
        sd += dv;
        float dx = dv * xv;
        #pragma unroll
        for (int s = 0; s < DS_; s++)
            h[s] = h[s] * __expf(dv * a[s]) + dx * Bsh[l][s];
    }
    size_t base = ((size_t)(b * DI_ + i) * NCH_ + c) * DS_;
    #pragma unroll
    for (int s = 0; s < DS_; s++) hL[base + s] = h[s];
    sdt[(size_t)(b * DI_ + i) * NCH_ + c] = sd;
}

// ============================================================
// scan mid: cross-chunk prefix (NCH_ chunks).  thread per (b,i,s)
// ============================================================
__global__ void k_scan_mid(const float* __restrict__ hL, const float* __restrict__ sdt,
                           const float* __restrict__ A_log, float* __restrict__ hin) {
    int idx = blockIdx.x * 256 + threadIdx.x;   // B_*DI_*DS_
    int s  = idx % DS_;
    int bi = idx / DS_;
    int i  = bi % DI_;
    float a = -__expf(A_log[(size_t)i * DS_ + s]);
    float hp = 0.f;
    size_t hbase = (size_t)bi * NCH_ * DS_ + s;
    for (int c = 0; c < NCH_; c++) {
        hin[hbase + (size_t)c * DS_] = hp;
        float sd = sdt[(size_t)bi * NCH_ + c];
        hp = hp * __expf(a * sd) + hL[hbase + (size_t)c * DS_];
    }
}

// ============================================================
// scan pass 2: recurrence with correct h_init; fused y = (scan + xc*Dskip)*silu(z)
// ============================================================
__global__ __launch_bounds__(256) void k_scan2(
        const float* __restrict__ dt, const float* __restrict__ xc,
        const float* __restrict__ dbc, const float* __restrict__ A_log,
        const float* __restrict__ hin, const float* __restrict__ Dskip,
        const float* __restrict__ xz, float* __restrict__ y) {
    int i = blockIdx.x * 256 + threadIdx.x;
    int b = blockIdx.y, c = blockIdx.z;
    __shared__ float Bsh[CL_][DS_];
    __shared__ float Csh[CL_][DS_];
    for (int t = threadIdx.x; t < CL_ * DS_; t += 256) {
        int l = t / DS_, s = t % DS_;
        size_t row = (size_t)(b * L_ + c * CL_ + l) * DBC_;
        Bsh[l][s] = dbc[row + DTR_ + s];
        Csh[l][s] = dbc[row + DTR_ + DS_ + s];
    }
    __syncthreads();
    float a[DS_];
    #pragma unroll
    for (int s = 0; s < DS_; s++) a[s] = -__expf(A_log[(size_t)i * DS_ + s]);
    float h[DS_];
    size_t hbase = ((size_t)(b * DI_ + i) * NCH_ + c) * DS_;
    #pragma unroll
    for (int s = 0; s < DS_; s++) h[s] = hin[hbase + s];
    float dsk = Dskip[i];
    const float* dtp = dt + (size_t)(b * L_ + c * CL_) * DI_ + i;
    const float* xcp = xc + (size_t)(b * L_ + c * CL_) * DI_ + i;
    const float* zp  = xz + (size_t)(b * L_ + c * CL_) * E2_ + DI_ + i;
    float* yp = y + (size_t)(b * L_ + c * CL_) * DI_ + i;
    for (int l = 0; l < CL_; l++) {
        float dv = dtp[(size_t)l * DI_];
        float xv = xcp[(size_t)l * DI_];
        float dx = dv * xv;
        float accv = 0.f;
        #pragma unroll
        for (int s = 0; s < DS_; s++) {
            h[s] = h[s] * __expf(dv * a[s]) + dx * Bsh[l][s];
            accv += h[s] * Csh[l][s];
        }
        float yv = accv + xv * dsk;
        float zv = zp[(size_t)l * E2_];
        float sig = 1.f / (1.f + __expf(-zv));
        yp[(size_t)l * DI_] = yv * (zv * sig);
    }
}

// ============================================================
// final head kernels
// ============================================================
__global__ void k_mean_partial(const float* __restrict__ xn, float* __restrict__ meanh) {
    int d  = blockIdx.x * 256 + threadIdx.x;   // grid.x = D_/256 = 3
    int b  = blockIdx.y;
    int lc = blockIdx.z;                        // 16 chunks of 64 rows
    float s = 0.f;
    for (int l = lc * 64; l < lc * 64 + 64; l++)
        s += xn[(size_t)(b * L_ + l) * D_ + d];
    atomicAdd(&meanh[b * D_ + d], s * (1.0f / L_));
}

__global__ void k_logits(const float* __restrict__ meanh, const float* __restrict__ cw,
                         const float* __restrict__ cb, float* __restrict__ out) {
    __shared__ float red[8][4];
    int t = threadIdx.x, wave = t >> 6, lane = t & 63;
    for (int bc = 0; bc < 8; bc++) {
        int b = bc >> 2, c = bc & 3;
        float s = 0.f;
        for (int d = t; d < D_; d += 256)
            s += meanh[b * D_ + d] * cw[(size_t)c * D_ + d];
        #pragma unroll
        for (int o = 32; o > 0; o >>= 1) s += __shfl_down(s, o);
        if (lane == 0) red[bc][wave] = s;
    }
    __syncthreads();
    if (t < 8) out[t] = red[t][0] + red[t][1] + red[t][2] + red[t][3] + cb[t & 3];
}

// ============================================================
// launcher
// ============================================================
extern "C" void kernel_launch(void* const* d_in, const int* in_sizes, int n_in,
                              void* d_out, int out_size, void* d_ws, size_t ws_size,
                              hipStream_t stream) {
    (void)in_sizes; (void)n_in; (void)out_size; (void)ws_size;
    const int*   ids   = (const int*)  d_in[0];
    const float* embed = (const float*)d_in[1];
    const float* normw = (const float*)d_in[2];
    const float* inw   = (const float*)d_in[3];
    const float* cw    = (const float*)d_in[4];
    const float* cb    = (const float*)d_in[5];
    const float* xpw   = (const float*)d_in[6];
    const float* dtw   = (const float*)d_in[7];
    const float* dtb   = (const float*)d_in[8];
    const float* Alog  = (const float*)d_in[9];
    const float* Dsk   = (const float*)d_in[10];
    const float* outw  = (const float*)d_in[11];
    const float* nfw   = (const float*)d_in[12];
    const float* clsw  = (const float*)d_in[13];
    const float* clsb  = (const float*)d_in[14];
    float* out = (float*)d_out;

    // workspace layout (floats)
    float* ws = (float*)d_ws;
    float* x     = ws;
    float* xn    = x    + (size_t)BL_ * D_;
    float* xz    = xn   + (size_t)BL_ * D_;
    float* xc    = xz   + (size_t)BL_ * E2_;
    float* dbc   = xc   + (size_t)BL_ * DI_;
    float* dtbuf = dbc  + (size_t)BL_ * DBC_;
    float* yg    = dtbuf+ (size_t)BL_ * DI_;
    float* hL    = yg   + (size_t)BL_ * DI_;
    float* hin   = hL   + (size_t)B_ * DI_ * NCH_ * DS_;
    float* sdt   = hin  + (size_t)B_ * DI_ * NCH_ * DS_;
    float* meanh = sdt  + (size_t)B_ * DI_ * NCH_;

    // embedding
    k_embed<<<BL_ * D_ / 4 / 256, 256, 0, stream>>>(ids, embed, x);

    for (int l = 0; l < NL_; l++) {
        const float* inw_l  = inw  + (size_t)l * E2_ * D_;
        const float* cw_l   = cw   + (size_t)l * DI_ * DC_;
        const float* cb_l   = cb   + (size_t)l * DI_;
        const float* xpw_l  = xpw  + (size_t)l * DBC_ * DI_;
        const float* dtw_l  = dtw  + (size_t)l * DI_ * DTR_;
        const float* dtb_l  = dtb  + (size_t)l * DI_;
        const float* Alog_l = Alog + (size_t)l * DI_ * DS_;
        const float* Dsk_l  = Dsk  + (size_t)l * DI_;
        const float* outw_l = outw + (size_t)l * D_ * DI_;
        const float* nw_l   = normw+ (size_t)l * D_;

        // rmsnorm
        k_rmsnorm<<<BL_, 192, 0, stream>>>(x, nw_l, xn);
        // in_proj: xz[2048,3072] = xn[2048,768] @ inw^T   (BM=128,BN=64)
        k_gemm_nt<8, 4, 32, 0><<<dim3(E2_ / 64, BL_ / 128), 256, 0, stream>>>(
            xn, inw_l, xz, nullptr, BL_, E2_, D_, D_, D_, E2_);
        // conv + silu
        k_conv_silu<<<BL_ * (DI_ / 256), 256, 0, stream>>>(xz, cw_l, cb_l, xc);
        // x_proj: dbc[2048,80] = xc @ xpw^T   (BM=64,BN=32)
        k_gemm_nt<4, 2, 32, 0><<<dim3((DBC_ + 31) / 32, BL_ / 64), 256, 0, stream>>>(
            xc, xpw_l, dbc, nullptr, BL_, DBC_, DI_, DI_, DI_, DBC_);
        // dt_proj + softplus: dt[2048,1536] = softplus(dbc[:, :48] @ dtw^T + dtb)
        k_gemm_nt<4, 4, 48, 1><<<dim3(DI_ / 64, BL_ / 64), 256, 0, stream>>>(
            dbc, dtw_l, dtbuf, dtb_l, BL_, DI_, DTR_, DBC_, DTR_, DI_);
        // chunked scan
        k_scan1<<<dim3(DI_ / 256, B_, NCH_), 256, 0, stream>>>(
            dtbuf, xc, dbc, Alog_l, hL, sdt);
        k_scan_mid<<<(B_ * DI_ * DS_) / 256, 256, 0, stream>>>(hL, sdt, Alog_l, hin);
        k_scan2<<<dim3(DI_ / 256, B_, NCH_), 256, 0, stream>>>(
            dtbuf, xc, dbc, Alog_l, hin, Dsk_l, xz, yg);
        // out_proj + residual: x += yg @ outw^T   (BM=64,BN=32)
        k_gemm_nt<4, 2, 32, 2><<<dim3(D_ / 32, BL_ / 64), 256, 0, stream>>>(
            yg, outw_l, x, nullptr, BL_, D_, DI_, DI_, DI_, D_);
    }

    // final rmsnorm -> xn
    k_rmsnorm<<<BL_, 192, 0, stream>>>(x, nfw, xn);
    // mean over L
    hipMemsetAsync(meanh, 0, (size_t)B_ * D_ * sizeof(float), stream);
    k_mean_partial<<<dim3(D_ / 256, B_, 16), 256, 0, stream>>>(xn, meanh);
    // logits
    k_logits<<<1, 256, 0, stream>>>(meanh, clsw, clsb, out);
}

// Round 4
// 1865.641 us; speedup vs baseline: 2.0160x; 2.0160x over previous
//
#include <hip/hip_runtime.h>
#include <hip/hip_bf16.h>
#include <math.h>

// ---- problem constants ----
#define V_    50280
#define D_    768
#define NL_   8
#define DI_   1536
#define DS_   16
#define DC_   4
#define DTR_  48
#define NC_   4
#define B_    2
#define L_    1024
#define BL_   (B_*L_)        // 2048
#define E2_   (2*DI_)        // 3072
#define DBC_  (DTR_+2*DS_)   // 80
#define EPS_  1e-5f
#define NCH_  32             // scan chunks
#define CL_   32             // chunk length
#define XSPLIT_ 12           // x_proj split-K factor (1536 = 12*128)

typedef unsigned short u16;
typedef unsigned int   u32;
typedef __bf16 bf16_t;
typedef bf16_t bf8v __attribute__((ext_vector_type(8)));
typedef float  f4v  __attribute__((ext_vector_type(4)));

#define AS1(p) ((const __attribute__((address_space(1))) void*)(p))
#define AS3(p) ((__attribute__((address_space(3))) void*)(p))

__device__ __forceinline__ u16 f2b(float f) {          // fp32 -> bf16 RNE
    u32 u = __float_as_uint(f);
    return (u16)((u + 0x7fffu + ((u >> 16) & 1u)) >> 16);
}

// ============================================================
// weight conversion kernels (run once per call, before the layer loop)
// ============================================================
__global__ void k_f2b(const float* __restrict__ in, u16* __restrict__ out, int n8) {
    int i = blockIdx.x * 256 + threadIdx.x;
    if (i >= n8) return;
    float4 a = *reinterpret_cast<const float4*>(in + (size_t)i * 8);
    float4 b = *reinterpret_cast<const float4*>(in + (size_t)i * 8 + 4);
    uint4 o;
    o.x = f2b(a.x) | ((u32)f2b(a.y) << 16);
    o.y = f2b(a.z) | ((u32)f2b(a.w) << 16);
    o.z = f2b(b.x) | ((u32)f2b(b.y) << 16);
    o.w = f2b(b.z) | ((u32)f2b(b.w) << 16);
    *reinterpret_cast<uint4*>(out + (size_t)i * 8) = o;
}

// xpw [NL][80][1536] -> xpwb [NL][128][1536] bf16, rows 80..127 zero
__global__ void k_xpw_cvt(const float* __restrict__ in, u16* __restrict__ out) {
    int i = blockIdx.x * 256 + threadIdx.x;      // unit of 8 along k; NL*128*192
    int k8 = i % (1536 / 8);
    int n  = (i / 192) % 128;
    int l  = i / (192 * 128);
    uint4 o = make_uint4(0, 0, 0, 0);
    if (n < 80) {
        const float* src = in + ((size_t)(l * 80 + n) * 1536) + k8 * 8;
        float4 a = *reinterpret_cast<const float4*>(src);
        float4 b = *reinterpret_cast<const float4*>(src + 4);
        o.x = f2b(a.x) | ((u32)f2b(a.y) << 16);
        o.y = f2b(a.z) | ((u32)f2b(a.w) << 16);
        o.z = f2b(b.x) | ((u32)f2b(b.y) << 16);
        o.w = f2b(b.z) | ((u32)f2b(b.w) << 16);
    }
    *reinterpret_cast<uint4*>(out + ((size_t)(l * 128 + n) * 1536) + k8 * 8) = o;
}

// dtw [NL][1536][48] -> dtwb [NL][1536][64] bf16, k 48..63 zero
__global__ void k_dtw_cvt(const float* __restrict__ in, u16* __restrict__ out) {
    int i = blockIdx.x * 256 + threadIdx.x;      // NL*1536*8 units
    int u  = i % 8;
    int ii = (i / 8) % 1536;
    int l  = i / (8 * 1536);
    uint4 o = make_uint4(0, 0, 0, 0);
    if (u < 6) {
        const float* src = in + ((size_t)(l * 1536 + ii) * 48) + u * 8;
        float4 a = *reinterpret_cast<const float4*>(src);
        float4 b = *reinterpret_cast<const float4*>(src + 4);
        o.x = f2b(a.x) | ((u32)f2b(a.y) << 16);
        o.y = f2b(a.z) | ((u32)f2b(a.w) << 16);
        o.z = f2b(b.x) | ((u32)f2b(b.y) << 16);
        o.w = f2b(b.z) | ((u32)f2b(b.w) << 16);
    }
    *reinterpret_cast<uint4*>(out + ((size_t)(l * 1536 + ii) * 64) + u * 8) = o;
}

// ============================================================
// embedding gather
// ============================================================
__global__ void k_embed(const int* __restrict__ ids, const float* __restrict__ embed,
                        float* __restrict__ x) {
    int idx = blockIdx.x * 256 + threadIdx.x;
    int row = idx / (D_/4);
    int col = (idx % (D_/4)) * 4;
    int id  = ids[row];
    float4 v = *reinterpret_cast<const float4*>(embed + (size_t)id * D_ + col);
    *reinterpret_cast<float4*>(x + (size_t)row * D_ + col) = v;
}

// ============================================================
// rmsnorm. OUT=0: fp32 out; OUT=1: bf16 out (feeds MFMA A operand)
// ============================================================
template<int OUT>
__global__ void k_rmsnorm(const float* __restrict__ in, const float* __restrict__ w,
                          float* __restrict__ outf, u16* __restrict__ outb) {
    int row = blockIdx.x;
    int t   = threadIdx.x;                     // 0..191
    float4 v = *reinterpret_cast<const float4*>(in + (size_t)row * D_ + t * 4);
    float ss = v.x*v.x + v.y*v.y + v.z*v.z + v.w*v.w;
    #pragma unroll
    for (int o = 32; o > 0; o >>= 1) ss += __shfl_down(ss, o);
    __shared__ float red[3];
    if ((t & 63) == 0) red[t >> 6] = ss;
    __syncthreads();
    float tot = red[0] + red[1] + red[2];
    float scale = rsqrtf(tot * (1.0f / D_) + EPS_);
    float4 wv = *reinterpret_cast<const float4*>(w + t * 4);
    float4 o4 = make_float4(v.x*scale*wv.x, v.y*scale*wv.y, v.z*scale*wv.z, v.w*scale*wv.w);
    if (OUT == 0) {
        *reinterpret_cast<float4*>(outf + (size_t)row * D_ + t * 4) = o4;
    } else {
        ushort4 u;
        u.x = f2b(o4.x); u.y = f2b(o4.y); u.z = f2b(o4.z); u.w = f2b(o4.w);
        *reinterpret_cast<ushort4*>(outb + (size_t)row * D_ + t * 4) = u;
    }
}

// ============================================================
// bf16 MFMA NT GEMM: C[2048,N] = A[2048,K]_bf16 * B[N,K]_bf16^T
// 128x128 tile, BK=32, 4 waves (2x2), double-buffered LDS,
// global_load_lds staging with XOR-swizzle (q ^= (row>>1)&3).
// EPI: 0 = store fp32, 1 = softplus(acc+bias[n]), 2 = C += acc
// SPLIT: blockIdx.z picks k-chunk, C offset by z*2048*ldc (partials)
// ============================================================
template<int EPI, bool SPLIT>
__global__ __launch_bounds__(256) void k_mfma_nt(
        const u16* __restrict__ A, const u16* __restrict__ B,
        float* __restrict__ C, const float* __restrict__ bias,
        int N, int lda, int ldb, int ldc, int kchunk) {
    __shared__ char smem[2][16384];            // per buf: A 8KB + B 8KB
    int tid = threadIdx.x;
    int m0 = blockIdx.y * 128, n0 = blockIdx.x * 128;
    int kbase = SPLIT ? blockIdx.z * kchunk : 0;
    int nk = kchunk / 32;
    if (SPLIT) C += (size_t)blockIdx.z * (size_t)BL_ * ldc;
    const u16* Abase = A + (size_t)m0 * lda + kbase;
    const u16* Bbase = B + (size_t)n0 * ldb + kbase;

    int lane = tid & 63;
    int wid  = tid >> 6;
    int wr = wid >> 1, wc = wid & 1;           // wave 2x2 grid, 64x64 out each
    int rb = lane & 15;                        // fragment row/col within 16
    int q  = lane >> 4;                        // k-slot (8 bf16 each)

    // swizzled LDS byte offsets for the 4 A-frags / 4 B-frags (fixed per lane)
    int aoff[4], boff[4];
    #pragma unroll
    for (int t = 0; t < 4; t++) {
        int row = wr * 64 + t * 16 + rb;
        aoff[t] = row * 64 + ((q ^ ((row >> 1) & 3)) << 4);
        int col = wc * 64 + t * 16 + rb;
        boff[t] = col * 64 + ((q ^ ((col >> 1) & 3)) << 4);
    }

    f4v acc[4][4];
    #pragma unroll
    for (int mi = 0; mi < 4; mi++)
        #pragma unroll
        for (int ni = 0; ni < 4; ni++)
            acc[mi][ni] = (f4v)0.0f;

    // stage one 128x32 A tile + 128x32 B tile into smem[buf]
    auto STAGE = [&](int buf, int kt) {
        const char* ga = (const char*)(Abase + kt * 32);
        const char* gb = (const char*)(Bbase + kt * 32);
        #pragma unroll
        for (int r2 = 0; r2 < 2; r2++) {
            int u = tid + r2 * 256;            // 16B unit: row=u>>2, slot=u&3
            int row = u >> 2, qq = u & 3;
            int qs = qq ^ ((row >> 1) & 3);    // pre-swizzled source (m173 pattern)
            __builtin_amdgcn_global_load_lds(
                AS1(ga + (size_t)row * (lda * 2) + qs * 16),
                AS3(&smem[buf][u * 16]), 16, 0, 0);
            __builtin_amdgcn_global_load_lds(
                AS1(gb + (size_t)row * (ldb * 2) + qs * 16),
                AS3(&smem[buf][8192 + u * 16]), 16, 0, 0);
        }
    };

    STAGE(0, 0);
    asm volatile("s_waitcnt vmcnt(0)" ::: "memory");
    __syncthreads();
    int cur = 0;
    for (int kt = 0; kt < nk; kt++) {
        if (kt + 1 < nk) STAGE(cur ^ 1, kt + 1);   // issue next-tile loads early
        bf8v af[4], bfr[4];
        #pragma unroll
        for (int t = 0; t < 4; t++) {
            af[t]  = *reinterpret_cast<const bf8v*>(&smem[cur][aoff[t]]);
            bfr[t] = *reinterpret_cast<const bf8v*>(&smem[cur][8192 + boff[t]]);
        }
        #pragma unroll
        for (int mi = 0; mi < 4; mi++)
            #pragma unroll
            for (int ni = 0; ni < 4; ni++)
                acc[mi][ni] = __builtin_amdgcn_mfma_f32_16x16x32_bf16(
                                  af[mi], bfr[ni], acc[mi][ni], 0, 0, 0);
        asm volatile("s_waitcnt vmcnt(0)" ::: "memory");
        __syncthreads();
        cur ^= 1;
    }

    // epilogue: C/D layout col=lane&15, row=(lane>>4)*4+reg  [m89/m91]
    #pragma unroll
    for (int mi = 0; mi < 4; mi++) {
        int grow = m0 + wr * 64 + mi * 16 + q * 4;
        #pragma unroll
        for (int ni = 0; ni < 4; ni++) {
            int gcol = n0 + wc * 64 + ni * 16 + rb;
            if (gcol >= N) continue;
            #pragma unroll
            for (int r = 0; r < 4; r++) {
                float v = acc[mi][ni][r];
                size_t off = (size_t)(grow + r) * ldc + gcol;
                if (EPI == 1) {
                    v += bias[gcol];
                    v = (v > 20.f) ? v : log1pf(__expf(v));
                    C[off] = v;
                } else if (EPI == 2) {
                    C[off] += v;
                } else {
                    C[off] = v;
                }
            }
        }
    }
}

// ============================================================
// causal depthwise conv (DC=4) + silu; writes fp32 (scan) + bf16 (x_proj A)
// thread handles 8 consecutive l for one channel i
// ============================================================
__global__ void k_conv_silu(const float* __restrict__ xz, const float* __restrict__ cw,
                            const float* __restrict__ cb, float* __restrict__ xc,
                            u16* __restrict__ xcb) {
    int i  = blockIdx.x * 256 + threadIdx.x;   // DI/256 = 6
    int b  = blockIdx.y;
    int l0 = blockIdx.z * 8;                   // L/8 = 128
    float4 w4 = *reinterpret_cast<const float4*>(cw + (size_t)i * DC_);
    float bias = cb[i];
    float v[11];
    #pragma unroll
    for (int t = 0; t < 11; t++) {
        int pos = l0 - 3 + t;
        v[t] = (pos >= 0) ? xz[(size_t)(b * L_ + pos) * E2_ + i] : 0.f;
    }
    #pragma unroll
    for (int j = 0; j < 8; j++) {
        float a = bias + v[j]*w4.x + v[j+1]*w4.y + v[j+2]*w4.z + v[j+3]*w4.w;
        float s = a / (1.f + __expf(-a));
        size_t off = (size_t)(b * L_ + l0 + j) * DI_ + i;
        xc[off]  = s;
        xcb[off] = f2b(s);
    }
}

// ============================================================
// x_proj split-K reduce: dbc fp32 (scan B/C) + dbcb bf16 K-padded (dt_proj A)
// ============================================================
__global__ void k_xreduce(const float* __restrict__ part, float* __restrict__ dbc,
                          u16* __restrict__ dbcb) {
    int idx = blockIdx.x * 256 + threadIdx.x;  // BL_*80
    int m = idx / 80, n = idx % 80;
    float s = 0.f;
    #pragma unroll
    for (int z = 0; z < XSPLIT_; z++) s += part[(size_t)z * BL_ * 80 + idx];
    dbc[idx] = s;
    if (n < 48)      dbcb[(size_t)m * 64 + n] = f2b(s);
    else if (n < 64) dbcb[(size_t)m * 64 + n] = 0;
}

// ============================================================
// scan pass 1: per-chunk local recurrence from h=0; final state + sum(dt)
// ============================================================
__global__ __launch_bounds__(256) void k_scan1(
        const float* __restrict__ dt, const float* __restrict__ xc,
        const float* __restrict__ dbc, const float* __restrict__ A_log,
        float* __restrict__ hL, float* __restrict__ sdt) {
    int i = blockIdx.x * 256 + threadIdx.x;
    int b = blockIdx.y, c = blockIdx.z;
    __shared__ float Bsh[CL_][DS_];
    for (int t = threadIdx.x; t < CL_ * DS_; t += 256) {
        int l = t / DS_, s = t % DS_;
        Bsh[l][s] = dbc[(size_t)(b * L_ + c * CL_ + l) * DBC_ + DTR_ + s];
    }
    __syncthreads();
    float a[DS_];
    #pragma unroll
    for (int s = 0; s < DS_; s++) a[s] = -__expf(A_log[(size_t)i * DS_ + s]);
    float h[DS_] = {};
    float sd = 0.f;
    const float* dtp = dt + (size_t)(b * L_ + c * CL_) * DI_ + i;
    const float* xcp = xc + (size_t)(b * L_ + c * CL_) * DI_ + i;
    for (int l = 0; l < CL_; l++) {
        float dv = dtp[(size_t)l * DI_];
        float xv = xcp[(size_t)l * DI_];
        sd += dv;
        float dx = dv * xv;
        #pragma unroll
        for (int s = 0; s < DS_; s++)
            h[s] = h[s] * __expf(dv * a[s]) + dx * Bsh[l][s];
    }
    size_t base = ((size_t)(b * DI_ + i) * NCH_ + c) * DS_;
    #pragma unroll
    for (int s = 0; s < DS_; s++) hL[base + s] = h[s];
    sdt[(size_t)(b * DI_ + i) * NCH_ + c] = sd;
}

// ============================================================
// scan mid: cross-chunk prefix
// ============================================================
__global__ void k_scan_mid(const float* __restrict__ hL, const float* __restrict__ sdt,
                           const float* __restrict__ A_log, float* __restrict__ hin) {
    int idx = blockIdx.x * 256 + threadIdx.x;   // B_*DI_*DS_
    int s  = idx % DS_;
    int bi = idx / DS_;
    int i  = bi % DI_;
    float a = -__expf(A_log[(size_t)i * DS_ + s]);
    float hp = 0.f;
    size_t hbase = (size_t)bi * NCH_ * DS_ + s;
    for (int c = 0; c < NCH_; c++) {
        hin[hbase + (size_t)c * DS_] = hp;
        float sd = sdt[(size_t)bi * NCH_ + c];
        hp = hp * __expf(a * sd) + hL[hbase + (size_t)c * DS_];
    }
}

// ============================================================
// scan pass 2: recurrence with h_init; y = (scan + xc*Dskip)*silu(z) -> bf16
// ============================================================
__global__ __launch_bounds__(256) void k_scan2(
        const float* __restrict__ dt, const float* __restrict__ xc,
        const float* __restrict__ dbc, const float* __restrict__ A_log,
        const float* __restrict__ hin, const float* __restrict__ Dskip,
        const float* __restrict__ xz, u16* __restrict__ ygb) {
    int i = blockIdx.x * 256 + threadIdx.x;
    int b = blockIdx.y, c = blockIdx.z;
    __shared__ float Bsh[CL_][DS_];
    __shared__ float Csh[CL_][DS_];
    for (int t = threadIdx.x; t < CL_ * DS_; t += 256) {
        int l = t / DS_, s = t % DS_;
        size_t row = (size_t)(b * L_ + c * CL_ + l) * DBC_;
        Bsh[l][s] = dbc[row + DTR_ + s];
        Csh[l][s] = dbc[row + DTR_ + DS_ + s];
    }
    __syncthreads();
    float a[DS_];
    #pragma unroll
    for (int s = 0; s < DS_; s++) a[s] = -__expf(A_log[(size_t)i * DS_ + s]);
    float h[DS_];
    size_t hbase = ((size_t)(b * DI_ + i) * NCH_ + c) * DS_;
    #pragma unroll
    for (int s = 0; s < DS_; s++) h[s] = hin[hbase + s];
    float dsk = Dskip[i];
    const float* dtp = dt + (size_t)(b * L_ + c * CL_) * DI_ + i;
    const float* xcp = xc + (size_t)(b * L_ + c * CL_) * DI_ + i;
    const float* zp  = xz + (size_t)(b * L_ + c * CL_) * E2_ + DI_ + i;
    u16* yp = ygb + (size_t)(b * L_ + c * CL_) * DI_ + i;
    for (int l = 0; l < CL_; l++) {
        float dv = dtp[(size_t)l * DI_];
        float xv = xcp[(size_t)l * DI_];
        float dx = dv * xv;
        float accv = 0.f;
        #pragma unroll
        for (int s = 0; s < DS_; s++) {
            h[s] = h[s] * __expf(dv * a[s]) + dx * Bsh[l][s];
            accv += h[s] * Csh[l][s];
        }
        float yv = accv + xv * dsk;
        float zv = zp[(size_t)l * E2_];
        float sig = 1.f / (1.f + __expf(-zv));
        yp[(size_t)l * DI_] = f2b(yv * (zv * sig));
    }
}

// ============================================================
// head
// ============================================================
__global__ void k_mean_partial(const float* __restrict__ xn, float* __restrict__ meanh) {
    int d  = blockIdx.x * 256 + threadIdx.x;
    int b  = blockIdx.y;
    int lc = blockIdx.z;
    float s = 0.f;
    for (int l = lc * 64; l < lc * 64 + 64; l++)
        s += xn[(size_t)(b * L_ + l) * D_ + d];
    atomicAdd(&meanh[b * D_ + d], s * (1.0f / L_));
}

__global__ void k_logits(const float* __restrict__ meanh, const float* __restrict__ cw,
                         const float* __restrict__ cb, float* __restrict__ out) {
    __shared__ float red[8][4];
    int t = threadIdx.x, wave = t >> 6, lane = t & 63;
    for (int bc = 0; bc < 8; bc++) {
        int b = bc >> 2, c = bc & 3;
        float s = 0.f;
        for (int d = t; d < D_; d += 256)
            s += meanh[b * D_ + d] * cw[(size_t)c * D_ + d];
        #pragma unroll
        for (int o = 32; o > 0; o >>= 1) s += __shfl_down(s, o);
        if (lane == 0) red[bc][wave] = s;
    }
    __syncthreads();
    if (t < 8) out[t] = red[t][0] + red[t][1] + red[t][2] + red[t][3] + cb[t & 3];
}

// ============================================================
// launcher
// ============================================================
extern "C" void kernel_launch(void* const* d_in, const int* in_sizes, int n_in,
                              void* d_out, int out_size, void* d_ws, size_t ws_size,
                              hipStream_t stream) {
    (void)in_sizes; (void)n_in; (void)out_size; (void)ws_size;
    const int*   ids   = (const int*)  d_in[0];
    const float* embed = (const float*)d_in[1];
    const float* normw = (const float*)d_in[2];
    const float* inw   = (const float*)d_in[3];
    const float* cw    = (const float*)d_in[4];
    const float* cb    = (const float*)d_in[5];
    const float* xpw   = (const float*)d_in[6];
    const float* dtw   = (const float*)d_in[7];
    const float* dtb   = (const float*)d_in[8];
    const float* Alog  = (const float*)d_in[9];
    const float* Dsk   = (const float*)d_in[10];
    const float* outw  = (const float*)d_in[11];
    const float* nfw   = (const float*)d_in[12];
    const float* clsw  = (const float*)d_in[13];
    const float* clsb  = (const float*)d_in[14];
    float* out = (float*)d_out;

    // ---- workspace layout (256B-aligned chunks) ----
    char* p = (char*)d_ws;
    auto alloc = [&](size_t bytes) { char* r = p; p += (bytes + 255) & ~(size_t)255; return r; };
    float* x     = (float*)alloc((size_t)BL_ * D_  * 4);
    float* xn    = (float*)alloc((size_t)BL_ * D_  * 4);
    float* xz    = (float*)alloc((size_t)BL_ * E2_ * 4);
    float* xc    = (float*)alloc((size_t)BL_ * DI_ * 4);
    u16*   xnb   = (u16*)  alloc((size_t)BL_ * D_  * 2);
    u16*   xcb   = (u16*)  alloc((size_t)BL_ * DI_ * 2);
    float* dbc   = (float*)alloc((size_t)BL_ * DBC_* 4);
    u16*   dbcb  = (u16*)  alloc((size_t)BL_ * 64  * 2);
    float* dtbuf = (float*)alloc((size_t)BL_ * DI_ * 4);
    u16*   ygb   = (u16*)  alloc((size_t)BL_ * DI_ * 2);
    float* xpart = (float*)alloc((size_t)XSPLIT_ * BL_ * 80 * 4);
    float* hL    = (float*)alloc((size_t)B_ * DI_ * NCH_ * DS_ * 4);
    float* hin   = (float*)alloc((size_t)B_ * DI_ * NCH_ * DS_ * 4);
    float* sdt   = (float*)alloc((size_t)B_ * DI_ * NCH_ * 4);
    float* meanh = (float*)alloc((size_t)B_ * D_ * 4);
    u16*   inwb  = (u16*)  alloc((size_t)NL_ * E2_ * D_  * 2);
    u16*   outwb = (u16*)  alloc((size_t)NL_ * D_  * DI_ * 2);
    u16*   xpwb  = (u16*)  alloc((size_t)NL_ * 128 * DI_ * 2);
    u16*   dtwb  = (u16*)  alloc((size_t)NL_ * DI_ * 64  * 2);

    // ---- weight conversion (identical work every call; graph-safe) ----
    k_f2b<<<(NL_*E2_*D_/8 + 255)/256, 256, 0, stream>>>(inw,  inwb,  NL_*E2_*D_/8);
    k_f2b<<<(NL_*D_*DI_/8 + 255)/256, 256, 0, stream>>>(outw, outwb, NL_*D_*DI_/8);
    k_xpw_cvt<<<NL_*128*192/256, 256, 0, stream>>>(xpw, xpwb);
    k_dtw_cvt<<<NL_*1536*8/256, 256, 0, stream>>>(dtw, dtwb);

    // embedding
    k_embed<<<BL_ * D_ / 4 / 256, 256, 0, stream>>>(ids, embed, x);

    for (int l = 0; l < NL_; l++) {
        const u16*   inwb_l = inwb + (size_t)l * E2_ * D_;
        const float* cw_l   = cw   + (size_t)l * DI_ * DC_;
        const float* cb_l   = cb   + (size_t)l * DI_;
        const u16*   xpwb_l = xpwb + (size_t)l * 128 * DI_;
        const u16*   dtwb_l = dtwb + (size_t)l * DI_ * 64;
        const float* dtb_l  = dtb  + (size_t)l * DI_;
        const float* Alog_l = Alog + (size_t)l * DI_ * DS_;
        const float* Dsk_l  = Dsk  + (size_t)l * DI_;
        const u16*   outwb_l= outwb+ (size_t)l * D_ * DI_;
        const float* nw_l   = normw+ (size_t)l * D_;

        // rmsnorm -> bf16
        k_rmsnorm<1><<<BL_, 192, 0, stream>>>(x, nw_l, nullptr, xnb);
        // in_proj: xz[2048,3072] = xnb @ inwb^T
        k_mfma_nt<0, false><<<dim3(E2_/128, BL_/128, 1), 256, 0, stream>>>(
            xnb, inwb_l, xz, nullptr, E2_, D_, D_, E2_, D_);
        // conv + silu -> xc fp32 + xcb bf16
        k_conv_silu<<<dim3(DI_/256, B_, L_/8), 256, 0, stream>>>(xz, cw_l, cb_l, xc, xcb);
        // x_proj split-K: partials[z][2048][80]
        k_mfma_nt<0, true><<<dim3(1, BL_/128, XSPLIT_), 256, 0, stream>>>(
            xcb, xpwb_l, xpart, nullptr, 80, DI_, DI_, 80, DI_/XSPLIT_);
        // reduce -> dbc fp32 + dbcb bf16 (K-padded 64)
        k_xreduce<<<BL_*80/256, 256, 0, stream>>>(xpart, dbc, dbcb);
        // dt_proj + softplus: dtbuf[2048,1536]
        k_mfma_nt<1, false><<<dim3(DI_/128, BL_/128, 1), 256, 0, stream>>>(
            dbcb, dtwb_l, dtbuf, dtb_l, DI_, 64, 64, DI_, 64);
        // chunked scan
        k_scan1<<<dim3(DI_/256, B_, NCH_), 256, 0, stream>>>(
            dtbuf, xc, dbc, Alog_l, hL, sdt);
        k_scan_mid<<<(B_*DI_*DS_)/256, 256, 0, stream>>>(hL, sdt, Alog_l, hin);
        k_scan2<<<dim3(DI_/256, B_, NCH_), 256, 0, stream>>>(
            dtbuf, xc, dbc, Alog_l, hin, Dsk_l, xz, ygb);
        // out_proj + residual: x += ygb @ outwb^T
        k_mfma_nt<2, false><<<dim3(D_/128, BL_/128, 1), 256, 0, stream>>>(
            ygb, outwb_l, x, nullptr, D_, DI_, DI_, D_, DI_);
    }

    // final rmsnorm -> fp32
    k_rmsnorm<0><<<BL_, 192, 0, stream>>>(x, nfw, xn, nullptr);
    hipMemsetAsync(meanh, 0, (size_t)B_ * D_ * sizeof(float), stream);
    k_mean_partial<<<dim3(D_/256, B_, 16), 256, 0, stream>>>(xn, meanh);
    k_logits<<<1, 256, 0, stream>>>(meanh, clsw, clsb, out);
}

// Round 6
// 1412.590 us; speedup vs baseline: 2.6626x; 1.3207x over previous
//
#include <hip/hip_runtime.h>
#include <hip/hip_bf16.h>
#include <math.h>

// ---- problem constants ----
#define V_    50280
#define D_    768
#define NL_   8
#define DI_   1536
#define DS_   16
#define DC_   4
#define DTR_  48
#define NC_   4
#define B_    2
#define L_    1024
#define BL_   (B_*L_)        // 2048
#define E2_   (2*DI_)        // 3072
#define DBC_  (DTR_+2*DS_)   // 80
#define EPS_  1e-5f
#define NCH_  32             // scan chunks
#define CL_   32             // chunk length
#define XSPLIT_ 12           // x_proj split-K factor (1536 = 12*128)

typedef unsigned short u16;
typedef unsigned int   u32;
typedef __bf16 bf16_t;
typedef bf16_t bf8v __attribute__((ext_vector_type(8)));
typedef float  f4v  __attribute__((ext_vector_type(4)));

#define AS1(p) ((const __attribute__((address_space(1))) void*)(p))
#define AS3(p) ((__attribute__((address_space(3))) void*)(p))

__device__ __forceinline__ u16 f2b(float f) {          // fp32 -> bf16 RNE
    u32 u = __float_as_uint(f);
    return (u16)((u + 0x7fffu + ((u >> 16) & 1u)) >> 16);
}

// native-rate, numerically-stable softplus
__device__ __forceinline__ float softplus_fast(float v) {
    return fmaxf(v, 0.f) + __logf(1.f + __expf(-fabsf(v)));
}

// ============================================================
// weight conversion kernels (run once per call, before the layer loop)
// ============================================================
__global__ void k_f2b(const float* __restrict__ in, u16* __restrict__ out, int n8) {
    int i = blockIdx.x * 256 + threadIdx.x;
    if (i >= n8) return;
    float4 a = *reinterpret_cast<const float4*>(in + (size_t)i * 8);
    float4 b = *reinterpret_cast<const float4*>(in + (size_t)i * 8 + 4);
    uint4 o;
    o.x = f2b(a.x) | ((u32)f2b(a.y) << 16);
    o.y = f2b(a.z) | ((u32)f2b(a.w) << 16);
    o.z = f2b(b.x) | ((u32)f2b(b.y) << 16);
    o.w = f2b(b.z) | ((u32)f2b(b.w) << 16);
    *reinterpret_cast<uint4*>(out + (size_t)i * 8) = o;
}

// xpw [NL][80][1536] -> xpwb [NL][128][1536] bf16, rows 80..127 zero
__global__ void k_xpw_cvt(const float* __restrict__ in, u16* __restrict__ out) {
    int i = blockIdx.x * 256 + threadIdx.x;      // unit of 8 along k; NL*128*192
    int k8 = i % (1536 / 8);
    int n  = (i / 192) % 128;
    int l  = i / (192 * 128);
    uint4 o = make_uint4(0, 0, 0, 0);
    if (n < 80) {
        const float* src = in + ((size_t)(l * 80 + n) * 1536) + k8 * 8;
        float4 a = *reinterpret_cast<const float4*>(src);
        float4 b = *reinterpret_cast<const float4*>(src + 4);
        o.x = f2b(a.x) | ((u32)f2b(a.y) << 16);
        o.y = f2b(a.z) | ((u32)f2b(a.w) << 16);
        o.z = f2b(b.x) | ((u32)f2b(b.y) << 16);
        o.w = f2b(b.z) | ((u32)f2b(b.w) << 16);
    }
    *reinterpret_cast<uint4*>(out + ((size_t)(l * 128 + n) * 1536) + k8 * 8) = o;
}

// ============================================================
// embedding gather
// ============================================================
__global__ void k_embed(const int* __restrict__ ids, const float* __restrict__ embed,
                        float* __restrict__ x) {
    int idx = blockIdx.x * 256 + threadIdx.x;
    int row = idx / (D_/4);
    int col = (idx % (D_/4)) * 4;
    int id  = ids[row];
    float4 v = *reinterpret_cast<const float4*>(embed + (size_t)id * D_ + col);
    *reinterpret_cast<float4*>(x + (size_t)row * D_ + col) = v;
}

// ============================================================
// rmsnorm. OUT=0: fp32 out; OUT=1: bf16 out (feeds MFMA A operand)
// ============================================================
template<int OUT>
__global__ void k_rmsnorm(const float* __restrict__ in, const float* __restrict__ w,
                          float* __restrict__ outf, u16* __restrict__ outb) {
    int row = blockIdx.x;
    int t   = threadIdx.x;                     // 0..191
    float4 v = *reinterpret_cast<const float4*>(in + (size_t)row * D_ + t * 4);
    float ss = v.x*v.x + v.y*v.y + v.z*v.z + v.w*v.w;
    #pragma unroll
    for (int o = 32; o > 0; o >>= 1) ss += __shfl_down(ss, o);
    __shared__ float red[3];
    if ((t & 63) == 0) red[t >> 6] = ss;
    __syncthreads();
    float tot = red[0] + red[1] + red[2];
    float scale = rsqrtf(tot * (1.0f / D_) + EPS_);
    float4 wv = *reinterpret_cast<const float4*>(w + t * 4);
    float4 o4 = make_float4(v.x*scale*wv.x, v.y*scale*wv.y, v.z*scale*wv.z, v.w*scale*wv.w);
    if (OUT == 0) {
        *reinterpret_cast<float4*>(outf + (size_t)row * D_ + t * 4) = o4;
    } else {
        ushort4 u;
        u.x = f2b(o4.x); u.y = f2b(o4.y); u.z = f2b(o4.z); u.w = f2b(o4.w);
        *reinterpret_cast<ushort4*>(outb + (size_t)row * D_ + t * 4) = u;
    }
}

// ============================================================
// bf16 MFMA NT GEMM: C[2048,N] = A[2048,K]_bf16 * B[N,K]_bf16^T
// 128x128 tile, BK=32, 4 waves (2x2), double-buffered LDS,
// global_load_lds staging with XOR-swizzle (q ^= (row>>1)&3).
// EPI: 0 = store fp32, 2 = C += acc
// SPLIT: blockIdx.z picks k-chunk, C offset by z*2048*ldc (partials)
// ============================================================
template<int EPI, bool SPLIT>
__global__ __launch_bounds__(256) void k_mfma_nt(
        const u16* __restrict__ A, const u16* __restrict__ B,
        float* __restrict__ C, const float* __restrict__ bias,
        int N, int lda, int ldb, int ldc, int kchunk) {
    __shared__ char smem[2][16384];            // per buf: A 8KB + B 8KB
    int tid = threadIdx.x;
    int m0 = blockIdx.y * 128, n0 = blockIdx.x * 128;
    int kbase = SPLIT ? blockIdx.z * kchunk : 0;
    int nk = kchunk / 32;
    if (SPLIT) C += (size_t)blockIdx.z * (size_t)BL_ * ldc;
    const u16* Abase = A + (size_t)m0 * lda + kbase;
    const u16* Bbase = B + (size_t)n0 * ldb + kbase;

    int lane = tid & 63;
    int wid  = tid >> 6;
    int wr = wid >> 1, wc = wid & 1;           // wave 2x2 grid, 64x64 out each
    int rb = lane & 15;                        // fragment row/col within 16
    int q  = lane >> 4;                        // k-slot (8 bf16 each)

    // swizzled LDS byte offsets for the 4 A-frags / 4 B-frags (fixed per lane)
    int aoff[4], boff[4];
    #pragma unroll
    for (int t = 0; t < 4; t++) {
        int row = wr * 64 + t * 16 + rb;
        aoff[t] = row * 64 + ((q ^ ((row >> 1) & 3)) << 4);
        int col = wc * 64 + t * 16 + rb;
        boff[t] = col * 64 + ((q ^ ((col >> 1) & 3)) << 4);
    }

    f4v acc[4][4];
    #pragma unroll
    for (int mi = 0; mi < 4; mi++)
        #pragma unroll
        for (int ni = 0; ni < 4; ni++)
            acc[mi][ni] = (f4v)0.0f;

    // stage one 128x32 A tile + 128x32 B tile into smem[buf]
    auto STAGE = [&](int buf, int kt) {
        const char* ga = (const char*)(Abase + kt * 32);
        const char* gb = (const char*)(Bbase + kt * 32);
        #pragma unroll
        for (int r2 = 0; r2 < 2; r2++) {
            int u = tid + r2 * 256;            // 16B unit: row=u>>2, slot=u&3
            int row = u >> 2, qq = u & 3;
            int qs = qq ^ ((row >> 1) & 3);    // pre-swizzled source (m173 pattern)
            __builtin_amdgcn_global_load_lds(
                AS1(ga + (size_t)row * (lda * 2) + qs * 16),
                AS3(&smem[buf][u * 16]), 16, 0, 0);
            __builtin_amdgcn_global_load_lds(
                AS1(gb + (size_t)row * (ldb * 2) + qs * 16),
                AS3(&smem[buf][8192 + u * 16]), 16, 0, 0);
        }
    };

    STAGE(0, 0);
    asm volatile("s_waitcnt vmcnt(0)" ::: "memory");
    __syncthreads();
    int cur = 0;
    for (int kt = 0; kt < nk; kt++) {
        if (kt + 1 < nk) STAGE(cur ^ 1, kt + 1);   // issue next-tile loads early
        bf8v af[4], bfr[4];
        #pragma unroll
        for (int t = 0; t < 4; t++) {
            af[t]  = *reinterpret_cast<const bf8v*>(&smem[cur][aoff[t]]);
            bfr[t] = *reinterpret_cast<const bf8v*>(&smem[cur][8192 + boff[t]]);
        }
        #pragma unroll
        for (int mi = 0; mi < 4; mi++)
            #pragma unroll
            for (int ni = 0; ni < 4; ni++)
                acc[mi][ni] = __builtin_amdgcn_mfma_f32_16x16x32_bf16(
                                  af[mi], bfr[ni], acc[mi][ni], 0, 0, 0);
        asm volatile("s_waitcnt vmcnt(0)" ::: "memory");
        __syncthreads();
        cur ^= 1;
    }

    // epilogue: C/D layout col=lane&15, row=(lane>>4)*4+reg  [m89/m91]
    #pragma unroll
    for (int mi = 0; mi < 4; mi++) {
        int grow = m0 + wr * 64 + mi * 16 + q * 4;
        #pragma unroll
        for (int ni = 0; ni < 4; ni++) {
            int gcol = n0 + wc * 64 + ni * 16 + rb;
            if (gcol >= N) continue;
            #pragma unroll
            for (int r = 0; r < 4; r++) {
                float v = acc[mi][ni][r];
                size_t off = (size_t)(grow + r) * ldc + gcol;
                if (EPI == 2) {
                    C[off] += v;
                } else {
                    C[off] = v;
                }
            }
        }
    }
}

// ============================================================
// causal depthwise conv (DC=4) + silu; writes fp32 (scan) + bf16 (x_proj A)
// ============================================================
__global__ void k_conv_silu(const float* __restrict__ xz, const float* __restrict__ cw,
                            const float* __restrict__ cb, float* __restrict__ xc,
                            u16* __restrict__ xcb) {
    int i  = blockIdx.x * 256 + threadIdx.x;   // DI/256 = 6
    int b  = blockIdx.y;
    int l0 = blockIdx.z * 8;                   // L/8 = 128
    float4 w4 = *reinterpret_cast<const float4*>(cw + (size_t)i * DC_);
    float bias = cb[i];
    float v[11];
    #pragma unroll
    for (int t = 0; t < 11; t++) {
        int pos = l0 - 3 + t;
        v[t] = (pos >= 0) ? xz[(size_t)(b * L_ + pos) * E2_ + i] : 0.f;
    }
    #pragma unroll
    for (int j = 0; j < 8; j++) {
        float a = bias + v[j]*w4.x + v[j+1]*w4.y + v[j+2]*w4.z + v[j+3]*w4.w;
        float s = a / (1.f + __expf(-a));
        size_t off = (size_t)(b * L_ + l0 + j) * DI_ + i;
        xc[off]  = s;
        xcb[off] = f2b(s);
    }
}

// ============================================================
// x_proj split-K reduce: dbc fp32 (consumed by fused scans)
// ============================================================
__global__ void k_xreduce(const float* __restrict__ part, float* __restrict__ dbc) {
    int idx = blockIdx.x * 256 + threadIdx.x;  // BL_*80
    float s = 0.f;
    #pragma unroll
    for (int z = 0; z < XSPLIT_; z++) s += part[(size_t)z * BL_ * 80 + idx];
    dbc[idx] = s;
}

// ============================================================
// scan pass 1 (FUSED dt_proj): per-chunk local recurrence from h=0.
// Stages the chunk's dbc rows [CL_][80] flat in LDS (contiguous copy);
// each thread holds dtw row (48 fp32) and computes
// dt = softplus(dbc[l,:48]·dtw[i] + dtb[i]) on the fly.
// grid (DI_/256, B_, NCH_)
// ============================================================
__global__ __launch_bounds__(256) void k_scan1(
        const float* __restrict__ xc, const float* __restrict__ dbc,
        const float* __restrict__ A_log, const float* __restrict__ dtw,
        const float* __restrict__ dtb,
        float* __restrict__ hL, float* __restrict__ sdt) {
    int i = blockIdx.x * 256 + threadIdx.x;
    int b = blockIdx.y, c = blockIdx.z;
    __shared__ float Dall[CL_ * DBC_];         // 32*80 floats = 10KB
    {
        const float4* src = reinterpret_cast<const float4*>(
            dbc + (size_t)(b * L_ + c * CL_) * DBC_);
        float4* dst = reinterpret_cast<float4*>(Dall);
        for (int t = threadIdx.x; t < CL_ * DBC_ / 4; t += 256) dst[t] = src[t];
    }
    __syncthreads();
    float a[DS_];
    #pragma unroll
    for (int s = 0; s < DS_; s++) a[s] = -__expf(A_log[(size_t)i * DS_ + s]);
    float w[DTR_];
    {
        const float4* wsrc = reinterpret_cast<const float4*>(dtw + (size_t)i * DTR_);
        #pragma unroll
        for (int j = 0; j < DTR_ / 4; j++) {
            float4 v = wsrc[j];
            w[j*4] = v.x; w[j*4+1] = v.y; w[j*4+2] = v.z; w[j*4+3] = v.w;
        }
    }
    float bias = dtb[i];
    float h[DS_] = {};
    float sd = 0.f;
    const float* xcp = xc + (size_t)(b * L_ + c * CL_) * DI_ + i;
    for (int l = 0; l < CL_; l++) {
        const float* Dl = &Dall[l * DBC_];
        float acc = bias;
        #pragma unroll
        for (int j = 0; j < DTR_; j++) acc += w[j] * Dl[j];   // LDS broadcast reads
        float dv = softplus_fast(acc);
        sd += dv;
        float dx = dv * xcp[(size_t)l * DI_];
        #pragma unroll
        for (int s = 0; s < DS_; s++)
            h[s] = h[s] * __expf(dv * a[s]) + dx * Dl[DTR_ + s];
    }
    size_t base = ((size_t)(b * DI_ + i) * NCH_ + c) * DS_;
    #pragma unroll
    for (int s = 0; s < DS_; s++) hL[base + s] = h[s];
    sdt[(size_t)(b * DI_ + i) * NCH_ + c] = sd;
}

// ============================================================
// scan mid: cross-chunk prefix
// ============================================================
__global__ void k_scan_mid(const float* __restrict__ hL, const float* __restrict__ sdt,
                           const float* __restrict__ A_log, float* __restrict__ hin) {
    int idx = blockIdx.x * 256 + threadIdx.x;   // B_*DI_*DS_
    int s  = idx % DS_;
    int bi = idx / DS_;
    int i  = bi % DI_;
    float a = -__expf(A_log[(size_t)i * DS_ + s]);
    float hp = 0.f;
    size_t hbase = (size_t)bi * NCH_ * DS_ + s;
    for (int c = 0; c < NCH_; c++) {
        hin[hbase + (size_t)c * DS_] = hp;
        float sd = sdt[(size_t)bi * NCH_ + c];
        hp = hp * __expf(a * sd) + hL[hbase + (size_t)c * DS_];
    }
}

// ============================================================
// scan pass 2 (FUSED dt_proj): recurrence with h_init;
// y = (scan + xc*Dskip)*silu(z) -> bf16
// ============================================================
__global__ __launch_bounds__(256) void k_scan2(
        const float* __restrict__ xc, const float* __restrict__ dbc,
        const float* __restrict__ A_log, const float* __restrict__ dtw,
        const float* __restrict__ dtb,
        const float* __restrict__ hin, const float* __restrict__ Dskip,
        const float* __restrict__ xz, u16* __restrict__ ygb) {
    int i = blockIdx.x * 256 + threadIdx.x;
    int b = blockIdx.y, c = blockIdx.z;
    __shared__ float Dall[CL_ * DBC_];
    {
        const float4* src = reinterpret_cast<const float4*>(
            dbc + (size_t)(b * L_ + c * CL_) * DBC_);
        float4* dst = reinterpret_cast<float4*>(Dall);
        for (int t = threadIdx.x; t < CL_ * DBC_ / 4; t += 256) dst[t] = src[t];
    }
    __syncthreads();
    float a[DS_];
    #pragma unroll
    for (int s = 0; s < DS_; s++) a[s] = -__expf(A_log[(size_t)i * DS_ + s]);
    float w[DTR_];
    {
        const float4* wsrc = reinterpret_cast<const float4*>(dtw + (size_t)i * DTR_);
        #pragma unroll
        for (int j = 0; j < DTR_ / 4; j++) {
            float4 v = wsrc[j];
            w[j*4] = v.x; w[j*4+1] = v.y; w[j*4+2] = v.z; w[j*4+3] = v.w;
        }
    }
    float bias = dtb[i];
    float h[DS_];
    size_t hbase = ((size_t)(b * DI_ + i) * NCH_ + c) * DS_;
    #pragma unroll
    for (int s = 0; s < DS_; s++) h[s] = hin[hbase + s];
    float dsk = Dskip[i];
    const float* xcp = xc + (size_t)(b * L_ + c * CL_) * DI_ + i;
    const float* zp  = xz + (size_t)(b * L_ + c * CL_) * E2_ + DI_ + i;
    u16* yp = ygb + (size_t)(b * L_ + c * CL_) * DI_ + i;
    for (int l = 0; l < CL_; l++) {
        const float* Dl = &Dall[l * DBC_];
        float acc = bias;
        #pragma unroll
        for (int j = 0; j < DTR_; j++) acc += w[j] * Dl[j];
        float dv = softplus_fast(acc);
        float xv = xcp[(size_t)l * DI_];
        float dx = dv * xv;
        float accv = 0.f;
        #pragma unroll
        for (int s = 0; s < DS_; s++) {
            h[s] = h[s] * __expf(dv * a[s]) + dx * Dl[DTR_ + s];
            accv += h[s] * Dl[DTR_ + DS_ + s];
        }
        float yv = accv + xv * dsk;
        float zv = zp[(size_t)l * E2_];
        float sig = 1.f / (1.f + __expf(-zv));
        yp[(size_t)l * DI_] = f2b(yv * (zv * sig));
    }
}

// ============================================================
// head
// ============================================================
__global__ void k_mean_partial(const float* __restrict__ xn, float* __restrict__ meanh) {
    int d  = blockIdx.x * 256 + threadIdx.x;
    int b  = blockIdx.y;
    int lc = blockIdx.z;
    float s = 0.f;
    for (int l = lc * 64; l < lc * 64 + 64; l++)
        s += xn[(size_t)(b * L_ + l) * D_ + d];
    atomicAdd(&meanh[b * D_ + d], s * (1.0f / L_));
}

__global__ void k_logits(const float* __restrict__ meanh, const float* __restrict__ cw,
                         const float* __restrict__ cb, float* __restrict__ out) {
    __shared__ float red[8][4];
    int t = threadIdx.x, wave = t >> 6, lane = t & 63;
    for (int bc = 0; bc < 8; bc++) {
        int b = bc >> 2, c = bc & 3;
        float s = 0.f;
        for (int d = t; d < D_; d += 256)
            s += meanh[b * D_ + d] * cw[(size_t)c * D_ + d];
        #pragma unroll
        for (int o = 32; o > 0; o >>= 1) s += __shfl_down(s, o);
        if (lane == 0) red[bc][wave] = s;
    }
    __syncthreads();
    if (t < 8) out[t] = red[t][0] + red[t][1] + red[t][2] + red[t][3] + cb[t & 3];
}

// ============================================================
// launcher
// ============================================================
extern "C" void kernel_launch(void* const* d_in, const int* in_sizes, int n_in,
                              void* d_out, int out_size, void* d_ws, size_t ws_size,
                              hipStream_t stream) {
    (void)in_sizes; (void)n_in; (void)out_size; (void)ws_size;
    const int*   ids   = (const int*)  d_in[0];
    const float* embed = (const float*)d_in[1];
    const float* normw = (const float*)d_in[2];
    const float* inw   = (const float*)d_in[3];
    const float* cw    = (const float*)d_in[4];
    const float* cb    = (const float*)d_in[5];
    const float* xpw   = (const float*)d_in[6];
    const float* dtw   = (const float*)d_in[7];
    const float* dtb   = (const float*)d_in[8];
    const float* Alog  = (const float*)d_in[9];
    const float* Dsk   = (const float*)d_in[10];
    const float* outw  = (const float*)d_in[11];
    const float* nfw   = (const float*)d_in[12];
    const float* clsw  = (const float*)d_in[13];
    const float* clsb  = (const float*)d_in[14];
    float* out = (float*)d_out;

    // ---- workspace layout (256B-aligned chunks) ----
    char* p = (char*)d_ws;
    auto alloc = [&](size_t bytes) { char* r = p; p += (bytes + 255) & ~(size_t)255; return r; };
    float* x     = (float*)alloc((size_t)BL_ * D_  * 4);
    float* xn    = (float*)alloc((size_t)BL_ * D_  * 4);
    float* xz    = (float*)alloc((size_t)BL_ * E2_ * 4);
    float* xc    = (float*)alloc((size_t)BL_ * DI_ * 4);
    u16*   xnb   = (u16*)  alloc((size_t)BL_ * D_  * 2);
    u16*   xcb   = (u16*)  alloc((size_t)BL_ * DI_ * 2);
    float* dbc   = (float*)alloc((size_t)BL_ * DBC_* 4);
    u16*   ygb   = (u16*)  alloc((size_t)BL_ * DI_ * 2);
    float* xpart = (float*)alloc((size_t)XSPLIT_ * BL_ * 80 * 4);
    float* hL    = (float*)alloc((size_t)B_ * DI_ * NCH_ * DS_ * 4);
    float* hin   = (float*)alloc((size_t)B_ * DI_ * NCH_ * DS_ * 4);
    float* sdt   = (float*)alloc((size_t)B_ * DI_ * NCH_ * 4);
    float* meanh = (float*)alloc((size_t)B_ * D_ * 4);
    u16*   inwb  = (u16*)  alloc((size_t)NL_ * E2_ * D_  * 2);
    u16*   outwb = (u16*)  alloc((size_t)NL_ * D_  * DI_ * 2);
    u16*   xpwb  = (u16*)  alloc((size_t)NL_ * 128 * DI_ * 2);

    // ---- weight conversion (identical work every call; graph-safe) ----
    k_f2b<<<(NL_*E2_*D_/8 + 255)/256, 256, 0, stream>>>(inw,  inwb,  NL_*E2_*D_/8);
    k_f2b<<<(NL_*D_*DI_/8 + 255)/256, 256, 0, stream>>>(outw, outwb, NL_*D_*DI_/8);
    k_xpw_cvt<<<NL_*128*192/256, 256, 0, stream>>>(xpw, xpwb);

    // embedding
    k_embed<<<BL_ * D_ / 4 / 256, 256, 0, stream>>>(ids, embed, x);

    for (int l = 0; l < NL_; l++) {
        const u16*   inwb_l = inwb + (size_t)l * E2_ * D_;
        const float* cw_l   = cw   + (size_t)l * DI_ * DC_;
        const float* cb_l   = cb   + (size_t)l * DI_;
        const u16*   xpwb_l = xpwb + (size_t)l * 128 * DI_;
        const float* dtw_l  = dtw  + (size_t)l * DI_ * DTR_;
        const float* dtb_l  = dtb  + (size_t)l * DI_;
        const float* Alog_l = Alog + (size_t)l * DI_ * DS_;
        const float* Dsk_l  = Dsk  + (size_t)l * DI_;
        const u16*   outwb_l= outwb+ (size_t)l * D_ * DI_;
        const float* nw_l   = normw+ (size_t)l * D_;

        // rmsnorm -> bf16
        k_rmsnorm<1><<<BL_, 192, 0, stream>>>(x, nw_l, nullptr, xnb);
        // in_proj: xz[2048,3072] = xnb @ inwb^T
        k_mfma_nt<0, false><<<dim3(E2_/128, BL_/128, 1), 256, 0, stream>>>(
            xnb, inwb_l, xz, nullptr, E2_, D_, D_, E2_, D_);
        // conv + silu -> xc fp32 + xcb bf16
        k_conv_silu<<<dim3(DI_/256, B_, L_/8), 256, 0, stream>>>(xz, cw_l, cb_l, xc, xcb);
        // x_proj split-K: partials[z][2048][80]
        k_mfma_nt<0, true><<<dim3(1, BL_/128, XSPLIT_), 256, 0, stream>>>(
            xcb, xpwb_l, xpart, nullptr, 80, DI_, DI_, 80, DI_/XSPLIT_);
        // reduce -> dbc fp32
        k_xreduce<<<BL_*80/256, 256, 0, stream>>>(xpart, dbc);
        // chunked scan with fused dt_proj (fp32, higher precision than before)
        k_scan1<<<dim3(DI_/256, B_, NCH_), 256, 0, stream>>>(
            xc, dbc, Alog_l, dtw_l, dtb_l, hL, sdt);
        k_scan_mid<<<(B_*DI_*DS_)/256, 256, 0, stream>>>(hL, sdt, Alog_l, hin);
        k_scan2<<<dim3(DI_/256, B_, NCH_), 256, 0, stream>>>(
            xc, dbc, Alog_l, dtw_l, dtb_l, hin, Dsk_l, xz, ygb);
        // out_proj + residual: x += ygb @ outwb^T
        k_mfma_nt<2, false><<<dim3(D_/128, BL_/128, 1), 256, 0, stream>>>(
            ygb, outwb_l, x, nullptr, D_, DI_, DI_, D_, DI_);
    }

    // final rmsnorm -> fp32
    k_rmsnorm<0><<<BL_, 192, 0, stream>>>(x, nfw, xn, nullptr);
    hipMemsetAsync(meanh, 0, (size_t)B_ * D_ * sizeof(float), stream);
    k_mean_partial<<<dim3(D_/256, B_, 16), 256, 0, stream>>>(xn, meanh);
    k_logits<<<1, 256, 0, stream>>>(meanh, clsw, clsb, out);
}

// Round 7
// 1362.496 us; speedup vs baseline: 2.7605x; 1.0368x over previous
//
#include <hip/hip_runtime.h>
#include <hip/hip_bf16.h>
#include <math.h>

// ---- problem constants ----
#define V_    50280
#define D_    768
#define NL_   8
#define DI_   1536
#define DS_   16
#define DC_   4
#define DTR_  48
#define NC_   4
#define B_    2
#define L_    1024
#define BL_   (B_*L_)        // 2048
#define E2_   (2*DI_)        // 3072
#define DBC_  (DTR_+2*DS_)   // 80
#define EPS_  1e-5f
#define NCH_  64             // scan chunks
#define CL_   16             // chunk length
#define XSPLIT_ 12           // x_proj split-K factor (1536 = 12*128)

typedef unsigned short u16;
typedef unsigned int   u32;
typedef __bf16 bf16_t;
typedef bf16_t bf8v __attribute__((ext_vector_type(8)));
typedef float  f4v  __attribute__((ext_vector_type(4)));

#define AS1(p) ((const __attribute__((address_space(1))) void*)(p))
#define AS3(p) ((__attribute__((address_space(3))) void*)(p))

__device__ __forceinline__ u16 f2b(float f) {          // fp32 -> bf16 RNE
    u32 u = __float_as_uint(f);
    return (u16)((u + 0x7fffu + ((u >> 16) & 1u)) >> 16);
}

// native-rate, numerically-stable softplus
__device__ __forceinline__ float softplus_fast(float v) {
    return fmaxf(v, 0.f) + __logf(1.f + __expf(-fabsf(v)));
}

// ============================================================
// weight conversion kernels (run once per call, before the layer loop)
// ============================================================
__global__ void k_f2b(const float* __restrict__ in, u16* __restrict__ out, int n8) {
    int i = blockIdx.x * 256 + threadIdx.x;
    if (i >= n8) return;
    float4 a = *reinterpret_cast<const float4*>(in + (size_t)i * 8);
    float4 b = *reinterpret_cast<const float4*>(in + (size_t)i * 8 + 4);
    uint4 o;
    o.x = f2b(a.x) | ((u32)f2b(a.y) << 16);
    o.y = f2b(a.z) | ((u32)f2b(a.w) << 16);
    o.z = f2b(b.x) | ((u32)f2b(b.y) << 16);
    o.w = f2b(b.z) | ((u32)f2b(b.w) << 16);
    *reinterpret_cast<uint4*>(out + (size_t)i * 8) = o;
}

// xpw [NL][80][1536] -> xpwb [NL][128][1536] bf16, rows 80..127 zero
__global__ void k_xpw_cvt(const float* __restrict__ in, u16* __restrict__ out) {
    int i = blockIdx.x * 256 + threadIdx.x;      // unit of 8 along k; NL*128*192
    int k8 = i % (1536 / 8);
    int n  = (i / 192) % 128;
    int l  = i / (192 * 128);
    uint4 o = make_uint4(0, 0, 0, 0);
    if (n < 80) {
        const float* src = in + ((size_t)(l * 80 + n) * 1536) + k8 * 8;
        float4 a = *reinterpret_cast<const float4*>(src);
        float4 b = *reinterpret_cast<const float4*>(src + 4);
        o.x = f2b(a.x) | ((u32)f2b(a.y) << 16);
        o.y = f2b(a.z) | ((u32)f2b(a.w) << 16);
        o.z = f2b(b.x) | ((u32)f2b(b.y) << 16);
        o.w = f2b(b.z) | ((u32)f2b(b.w) << 16);
    }
    *reinterpret_cast<uint4*>(out + ((size_t)(l * 128 + n) * 1536) + k8 * 8) = o;
}

// ============================================================
// embedding gather
// ============================================================
__global__ void k_embed(const int* __restrict__ ids, const float* __restrict__ embed,
                        float* __restrict__ x) {
    int idx = blockIdx.x * 256 + threadIdx.x;
    int row = idx / (D_/4);
    int col = (idx % (D_/4)) * 4;
    int id  = ids[row];
    float4 v = *reinterpret_cast<const float4*>(embed + (size_t)id * D_ + col);
    *reinterpret_cast<float4*>(x + (size_t)row * D_ + col) = v;
}

// ============================================================
// rmsnorm. OUT=0: fp32 out; OUT=1: bf16 out (feeds MFMA A operand)
// ============================================================
template<int OUT>
__global__ void k_rmsnorm(const float* __restrict__ in, const float* __restrict__ w,
                          float* __restrict__ outf, u16* __restrict__ outb) {
    int row = blockIdx.x;
    int t   = threadIdx.x;                     // 0..191
    float4 v = *reinterpret_cast<const float4*>(in + (size_t)row * D_ + t * 4);
    float ss = v.x*v.x + v.y*v.y + v.z*v.z + v.w*v.w;
    #pragma unroll
    for (int o = 32; o > 0; o >>= 1) ss += __shfl_down(ss, o);
    __shared__ float red[3];
    if ((t & 63) == 0) red[t >> 6] = ss;
    __syncthreads();
    float tot = red[0] + red[1] + red[2];
    float scale = rsqrtf(tot * (1.0f / D_) + EPS_);
    float4 wv = *reinterpret_cast<const float4*>(w + t * 4);
    float4 o4 = make_float4(v.x*scale*wv.x, v.y*scale*wv.y, v.z*scale*wv.z, v.w*scale*wv.w);
    if (OUT == 0) {
        *reinterpret_cast<float4*>(outf + (size_t)row * D_ + t * 4) = o4;
    } else {
        ushort4 u;
        u.x = f2b(o4.x); u.y = f2b(o4.y); u.z = f2b(o4.z); u.w = f2b(o4.w);
        *reinterpret_cast<ushort4*>(outb + (size_t)row * D_ + t * 4) = u;
    }
}

// ============================================================
// bf16 MFMA NT GEMM: C[2048,N] = A[2048,K]_bf16 * B[N,K]_bf16^T
// 128x128 tile, BK=32, 4 waves (2x2), double-buffered LDS,
// global_load_lds staging with XOR-swizzle (q ^= (row>>1)&3).
// Counted-vmcnt single-barrier pipeline: each iteration waits on the
// loads issued ONE ITERATION earlier (full loop body of latency cover),
// not the same-iteration loads.
// EPI: 0 = store fp32, 2 = C += acc
// SPLIT: blockIdx.z picks k-chunk, C offset by z*2048*ldc (partials)
// ============================================================
template<int EPI, bool SPLIT>
__global__ __launch_bounds__(256) void k_mfma_nt(
        const u16* __restrict__ A, const u16* __restrict__ B,
        float* __restrict__ C, const float* __restrict__ bias,
        int N, int lda, int ldb, int ldc, int kchunk) {
    __shared__ char smem[2][16384];            // per buf: A 8KB + B 8KB
    int tid = threadIdx.x;
    int m0 = blockIdx.y * 128, n0 = blockIdx.x * 128;
    int kbase = SPLIT ? blockIdx.z * kchunk : 0;
    int nk = kchunk / 32;
    if (SPLIT) C += (size_t)blockIdx.z * (size_t)BL_ * ldc;
    const u16* Abase = A + (size_t)m0 * lda + kbase;
    const u16* Bbase = B + (size_t)n0 * ldb + kbase;

    int lane = tid & 63;
    int wid  = tid >> 6;
    int wr = wid >> 1, wc = wid & 1;           // wave 2x2 grid, 64x64 out each
    int rb = lane & 15;                        // fragment row/col within 16
    int q  = lane >> 4;                        // k-slot (8 bf16 each)

    // swizzled LDS byte offsets for the 4 A-frags / 4 B-frags (fixed per lane)
    int aoff[4], boff[4];
    #pragma unroll
    for (int t = 0; t < 4; t++) {
        int row = wr * 64 + t * 16 + rb;
        aoff[t] = row * 64 + ((q ^ ((row >> 1) & 3)) << 4);
        int col = wc * 64 + t * 16 + rb;
        boff[t] = col * 64 + ((q ^ ((col >> 1) & 3)) << 4);
    }

    f4v acc[4][4];
    #pragma unroll
    for (int mi = 0; mi < 4; mi++)
        #pragma unroll
        for (int ni = 0; ni < 4; ni++)
            acc[mi][ni] = (f4v)0.0f;

    // stage one 128x32 A tile + 128x32 B tile into smem[buf] (4 loads/lane)
    auto STAGE = [&](int buf, int kt) {
        const char* ga = (const char*)(Abase + kt * 32);
        const char* gb = (const char*)(Bbase + kt * 32);
        #pragma unroll
        for (int r2 = 0; r2 < 2; r2++) {
            int u = tid + r2 * 256;            // 16B unit: row=u>>2, slot=u&3
            int row = u >> 2, qq = u & 3;
            int qs = qq ^ ((row >> 1) & 3);    // pre-swizzled source (m173 pattern)
            __builtin_amdgcn_global_load_lds(
                AS1(ga + (size_t)row * (lda * 2) + qs * 16),
                AS3(&smem[buf][u * 16]), 16, 0, 0);
            __builtin_amdgcn_global_load_lds(
                AS1(gb + (size_t)row * (ldb * 2) + qs * 16),
                AS3(&smem[buf][8192 + u * 16]), 16, 0, 0);
        }
    };

    STAGE(0, 0);
    int cur = 0;
    for (int kt = 0; kt < nk; kt++) {
        // wait for tile kt's loads (issued one iteration ago except kt=0)
        asm volatile("s_waitcnt vmcnt(0)" ::: "memory");
        // collective: tile kt resident AND everyone done reading buf[cur^1]
        __builtin_amdgcn_s_barrier();
        if (kt + 1 < nk) STAGE(cur ^ 1, kt + 1);   // prefetch next tile
        bf8v af[4], bfr[4];
        #pragma unroll
        for (int t = 0; t < 4; t++) {
            af[t]  = *reinterpret_cast<const bf8v*>(&smem[cur][aoff[t]]);
            bfr[t] = *reinterpret_cast<const bf8v*>(&smem[cur][8192 + boff[t]]);
        }
        #pragma unroll
        for (int mi = 0; mi < 4; mi++)
            #pragma unroll
            for (int ni = 0; ni < 4; ni++)
                acc[mi][ni] = __builtin_amdgcn_mfma_f32_16x16x32_bf16(
                                  af[mi], bfr[ni], acc[mi][ni], 0, 0, 0);
        cur ^= 1;
    }

    // epilogue: C/D layout col=lane&15, row=(lane>>4)*4+reg  [m89/m91]
    #pragma unroll
    for (int mi = 0; mi < 4; mi++) {
        int grow = m0 + wr * 64 + mi * 16 + q * 4;
        #pragma unroll
        for (int ni = 0; ni < 4; ni++) {
            int gcol = n0 + wc * 64 + ni * 16 + rb;
            if (gcol >= N) continue;
            #pragma unroll
            for (int r = 0; r < 4; r++) {
                float v = acc[mi][ni][r];
                size_t off = (size_t)(grow + r) * ldc + gcol;
                if (EPI == 2) {
                    C[off] += v;
                } else {
                    C[off] = v;
                }
            }
        }
    }
}

// ============================================================
// causal depthwise conv (DC=4) + silu; writes fp32 (scan) + bf16 (x_proj A)
// ============================================================
__global__ void k_conv_silu(const float* __restrict__ xz, const float* __restrict__ cw,
                            const float* __restrict__ cb, float* __restrict__ xc,
                            u16* __restrict__ xcb) {
    int i  = blockIdx.x * 256 + threadIdx.x;   // DI/256 = 6
    int b  = blockIdx.y;
    int l0 = blockIdx.z * 8;                   // L/8 = 128
    float4 w4 = *reinterpret_cast<const float4*>(cw + (size_t)i * DC_);
    float bias = cb[i];
    float v[11];
    #pragma unroll
    for (int t = 0; t < 11; t++) {
        int pos = l0 - 3 + t;
        v[t] = (pos >= 0) ? xz[(size_t)(b * L_ + pos) * E2_ + i] : 0.f;
    }
    #pragma unroll
    for (int j = 0; j < 8; j++) {
        float a = bias + v[j]*w4.x + v[j+1]*w4.y + v[j+2]*w4.z + v[j+3]*w4.w;
        float s = a / (1.f + __expf(-a));
        size_t off = (size_t)(b * L_ + l0 + j) * DI_ + i;
        xc[off]  = s;
        xcb[off] = f2b(s);
    }
}

// ============================================================
// scan pass 1 (FUSED dt_proj + x_proj 12-way reduce): per-chunk local
// recurrence from h=0. Stages reduced dbc rows [CL_][80] in LDS (the
// 12 partials are summed during staging); block x==0 also writes the
// reduced chunk to global dbc for scan2.
// grid (DI_/256, B_, NCH_)
// ============================================================
__global__ __launch_bounds__(256) void k_scan1(
        const float* __restrict__ xc, const float* __restrict__ part,
        float* __restrict__ dbc,
        const float* __restrict__ A_log, const float* __restrict__ dtw,
        const float* __restrict__ dtb,
        float* __restrict__ hL, float* __restrict__ sdt) {
    int i = blockIdx.x * 256 + threadIdx.x;
    int b = blockIdx.y, c = blockIdx.z;
    __shared__ float Dall[CL_ * DBC_];         // 16*80 floats = 5KB
    {
        size_t base4 = (size_t)(b * L_ + c * CL_) * DBC_ / 4;
        float4* dst = reinterpret_cast<float4*>(Dall);
        const float4* p4 = reinterpret_cast<const float4*>(part);
        float4* dbc4 = reinterpret_cast<float4*>(dbc);
        for (int t = threadIdx.x; t < CL_ * DBC_ / 4; t += 256) {
            float4 s = make_float4(0.f, 0.f, 0.f, 0.f);
            #pragma unroll
            for (int z = 0; z < XSPLIT_; z++) {
                float4 v = p4[(size_t)z * (BL_ * DBC_ / 4) + base4 + t];
                s.x += v.x; s.y += v.y; s.z += v.z; s.w += v.w;
            }
            dst[t] = s;
            if (blockIdx.x == 0) dbc4[base4 + t] = s;   // reduced dbc for scan2
        }
    }
    __syncthreads();
    float a[DS_];
    #pragma unroll
    for (int s = 0; s < DS_; s++) a[s] = -__expf(A_log[(size_t)i * DS_ + s]);
    float w[DTR_];
    {
        const float4* wsrc = reinterpret_cast<const float4*>(dtw + (size_t)i * DTR_);
        #pragma unroll
        for (int j = 0; j < DTR_ / 4; j++) {
            float4 v = wsrc[j];
            w[j*4] = v.x; w[j*4+1] = v.y; w[j*4+2] = v.z; w[j*4+3] = v.w;
        }
    }
    float bias = dtb[i];
    float h[DS_] = {};
    float sd = 0.f;
    const float* xcp = xc + (size_t)(b * L_ + c * CL_) * DI_ + i;
    for (int l = 0; l < CL_; l++) {
        const float* Dl = &Dall[l * DBC_];
        float acc = bias;
        #pragma unroll
        for (int j = 0; j < DTR_; j++) acc += w[j] * Dl[j];   // LDS broadcast reads
        float dv = softplus_fast(acc);
        sd += dv;
        float dx = dv * xcp[(size_t)l * DI_];
        #pragma unroll
        for (int s = 0; s < DS_; s++)
            h[s] = h[s] * __expf(dv * a[s]) + dx * Dl[DTR_ + s];
    }
    size_t base = ((size_t)(b * DI_ + i) * NCH_ + c) * DS_;
    #pragma unroll
    for (int s = 0; s < DS_; s++) hL[base + s] = h[s];
    sdt[(size_t)(b * DI_ + i) * NCH_ + c] = sd;
}

// ============================================================
// scan mid: cross-chunk prefix
// ============================================================
__global__ void k_scan_mid(const float* __restrict__ hL, const float* __restrict__ sdt,
                           const float* __restrict__ A_log, float* __restrict__ hin) {
    int idx = blockIdx.x * 256 + threadIdx.x;   // B_*DI_*DS_
    int s  = idx % DS_;
    int bi = idx / DS_;
    int i  = bi % DI_;
    float a = -__expf(A_log[(size_t)i * DS_ + s]);
    float hp = 0.f;
    size_t hbase = (size_t)bi * NCH_ * DS_ + s;
    for (int c = 0; c < NCH_; c++) {
        hin[hbase + (size_t)c * DS_] = hp;
        float sd = sdt[(size_t)bi * NCH_ + c];
        hp = hp * __expf(a * sd) + hL[hbase + (size_t)c * DS_];
    }
}

// ============================================================
// scan pass 2 (FUSED dt_proj): recurrence with h_init;
// y = (scan + xc*Dskip)*silu(z) -> bf16
// ============================================================
__global__ __launch_bounds__(256) void k_scan2(
        const float* __restrict__ xc, const float* __restrict__ dbc,
        const float* __restrict__ A_log, const float* __restrict__ dtw,
        const float* __restrict__ dtb,
        const float* __restrict__ hin, const float* __restrict__ Dskip,
        const float* __restrict__ xz, u16* __restrict__ ygb) {
    int i = blockIdx.x * 256 + threadIdx.x;
    int b = blockIdx.y, c = blockIdx.z;
    __shared__ float Dall[CL_ * DBC_];
    {
        const float4* src = reinterpret_cast<const float4*>(
            dbc + (size_t)(b * L_ + c * CL_) * DBC_);
        float4* dst = reinterpret_cast<float4*>(Dall);
        for (int t = threadIdx.x; t < CL_ * DBC_ / 4; t += 256) dst[t] = src[t];
    }
    __syncthreads();
    float a[DS_];
    #pragma unroll
    for (int s = 0; s < DS_; s++) a[s] = -__expf(A_log[(size_t)i * DS_ + s]);
    float w[DTR_];
    {
        const float4* wsrc = reinterpret_cast<const float4*>(dtw + (size_t)i * DTR_);
        #pragma unroll
        for (int j = 0; j < DTR_ / 4; j++) {
            float4 v = wsrc[j];
            w[j*4] = v.x; w[j*4+1] = v.y; w[j*4+2] = v.z; w[j*4+3] = v.w;
        }
    }
    float bias = dtb[i];
    float h[DS_];
    size_t hbase = ((size_t)(b * DI_ + i) * NCH_ + c) * DS_;
    #pragma unroll
    for (int s = 0; s < DS_; s++) h[s] = hin[hbase + s];
    float dsk = Dskip[i];
    const float* xcp = xc + (size_t)(b * L_ + c * CL_) * DI_ + i;
    const float* zp  = xz + (size_t)(b * L_ + c * CL_) * E2_ + DI_ + i;
    u16* yp = ygb + (size_t)(b * L_ + c * CL_) * DI_ + i;
    for (int l = 0; l < CL_; l++) {
        const float* Dl = &Dall[l * DBC_];
        float acc = bias;
        #pragma unroll
        for (int j = 0; j < DTR_; j++) acc += w[j] * Dl[j];
        float dv = softplus_fast(acc);
        float xv = xcp[(size_t)l * DI_];
        float dx = dv * xv;
        float accv = 0.f;
        #pragma unroll
        for (int s = 0; s < DS_; s++) {
            h[s] = h[s] * __expf(dv * a[s]) + dx * Dl[DTR_ + s];
            accv += h[s] * Dl[DTR_ + DS_ + s];
        }
        float yv = accv + xv * dsk;
        float zv = zp[(size_t)l * E2_];
        float sig = 1.f / (1.f + __expf(-zv));
        yp[(size_t)l * DI_] = f2b(yv * (zv * sig));
    }
}

// ============================================================
// head
// ============================================================
__global__ void k_mean_partial(const float* __restrict__ xn, float* __restrict__ meanh) {
    int d  = blockIdx.x * 256 + threadIdx.x;
    int b  = blockIdx.y;
    int lc = blockIdx.z;
    float s = 0.f;
    for (int l = lc * 64; l < lc * 64 + 64; l++)
        s += xn[(size_t)(b * L_ + l) * D_ + d];
    atomicAdd(&meanh[b * D_ + d], s * (1.0f / L_));
}

__global__ void k_logits(const float* __restrict__ meanh, const float* __restrict__ cw,
                         const float* __restrict__ cb, float* __restrict__ out) {
    __shared__ float red[8][4];
    int t = threadIdx.x, wave = t >> 6, lane = t & 63;
    for (int bc = 0; bc < 8; bc++) {
        int b = bc >> 2, c = bc & 3;
        float s = 0.f;
        for (int d = t; d < D_; d += 256)
            s += meanh[b * D_ + d] * cw[(size_t)c * D_ + d];
        #pragma unroll
        for (int o = 32; o > 0; o >>= 1) s += __shfl_down(s, o);
        if (lane == 0) red[bc][wave] = s;
    }
    __syncthreads();
    if (t < 8) out[t] = red[t][0] + red[t][1] + red[t][2] + red[t][3] + cb[t & 3];
}

// ============================================================
// launcher
// ============================================================
extern "C" void kernel_launch(void* const* d_in, const int* in_sizes, int n_in,
                              void* d_out, int out_size, void* d_ws, size_t ws_size,
                              hipStream_t stream) {
    (void)in_sizes; (void)n_in; (void)out_size; (void)ws_size;
    const int*   ids   = (const int*)  d_in[0];
    const float* embed = (const float*)d_in[1];
    const float* normw = (const float*)d_in[2];
    const float* inw   = (const float*)d_in[3];
    const float* cw    = (const float*)d_in[4];
    const float* cb    = (const float*)d_in[5];
    const float* xpw   = (const float*)d_in[6];
    const float* dtw   = (const float*)d_in[7];
    const float* dtb   = (const float*)d_in[8];
    const float* Alog  = (const float*)d_in[9];
    const float* Dsk   = (const float*)d_in[10];
    const float* outw  = (const float*)d_in[11];
    const float* nfw   = (const float*)d_in[12];
    const float* clsw  = (const float*)d_in[13];
    const float* clsb  = (const float*)d_in[14];
    float* out = (float*)d_out;

    // ---- workspace layout (256B-aligned chunks) ----
    char* p = (char*)d_ws;
    auto alloc = [&](size_t bytes) { char* r = p; p += (bytes + 255) & ~(size_t)255; return r; };
    float* x     = (float*)alloc((size_t)BL_ * D_  * 4);
    float* xn    = (float*)alloc((size_t)BL_ * D_  * 4);
    float* xz    = (float*)alloc((size_t)BL_ * E2_ * 4);
    float* xc    = (float*)alloc((size_t)BL_ * DI_ * 4);
    u16*   xnb   = (u16*)  alloc((size_t)BL_ * D_  * 2);
    u16*   xcb   = (u16*)  alloc((size_t)BL_ * DI_ * 2);
    float* dbc   = (float*)alloc((size_t)BL_ * DBC_* 4);
    u16*   ygb   = (u16*)  alloc((size_t)BL_ * DI_ * 2);
    float* xpart = (float*)alloc((size_t)XSPLIT_ * BL_ * DBC_ * 4);
    float* hL    = (float*)alloc((size_t)B_ * DI_ * NCH_ * DS_ * 4);
    float* hin   = (float*)alloc((size_t)B_ * DI_ * NCH_ * DS_ * 4);
    float* sdt   = (float*)alloc((size_t)B_ * DI_ * NCH_ * 4);
    float* meanh = (float*)alloc((size_t)B_ * D_ * 4);
    u16*   inwb  = (u16*)  alloc((size_t)NL_ * E2_ * D_  * 2);
    u16*   outwb = (u16*)  alloc((size_t)NL_ * D_  * DI_ * 2);
    u16*   xpwb  = (u16*)  alloc((size_t)NL_ * 128 * DI_ * 2);

    // ---- weight conversion (identical work every call; graph-safe) ----
    k_f2b<<<(NL_*E2_*D_/8 + 255)/256, 256, 0, stream>>>(inw,  inwb,  NL_*E2_*D_/8);
    k_f2b<<<(NL_*D_*DI_/8 + 255)/256, 256, 0, stream>>>(outw, outwb, NL_*D_*DI_/8);
    k_xpw_cvt<<<NL_*128*192/256, 256, 0, stream>>>(xpw, xpwb);

    // embedding
    k_embed<<<BL_ * D_ / 4 / 256, 256, 0, stream>>>(ids, embed, x);

    for (int l = 0; l < NL_; l++) {
        const u16*   inwb_l = inwb + (size_t)l * E2_ * D_;
        const float* cw_l   = cw   + (size_t)l * DI_ * DC_;
        const float* cb_l   = cb   + (size_t)l * DI_;
        const u16*   xpwb_l = xpwb + (size_t)l * 128 * DI_;
        const float* dtw_l  = dtw  + (size_t)l * DI_ * DTR_;
        const float* dtb_l  = dtb  + (size_t)l * DI_;
        const float* Alog_l = Alog + (size_t)l * DI_ * DS_;
        const float* Dsk_l  = Dsk  + (size_t)l * DI_;
        const u16*   outwb_l= outwb+ (size_t)l * D_ * DI_;
        const float* nw_l   = normw+ (size_t)l * D_;

        // rmsnorm -> bf16
        k_rmsnorm<1><<<BL_, 192, 0, stream>>>(x, nw_l, nullptr, xnb);
        // in_proj: xz[2048,3072] = xnb @ inwb^T
        k_mfma_nt<0, false><<<dim3(E2_/128, BL_/128, 1), 256, 0, stream>>>(
            xnb, inwb_l, xz, nullptr, E2_, D_, D_, E2_, D_);
        // conv + silu -> xc fp32 + xcb bf16
        k_conv_silu<<<dim3(DI_/256, B_, L_/8), 256, 0, stream>>>(xz, cw_l, cb_l, xc, xcb);
        // x_proj split-K: partials[z][2048][80]
        k_mfma_nt<0, true><<<dim3(1, BL_/128, XSPLIT_), 256, 0, stream>>>(
            xcb, xpwb_l, xpart, nullptr, DBC_, DI_, DI_, DBC_, DI_/XSPLIT_);
        // scan1: fused 12-way reduce + dt_proj + local recurrence
        k_scan1<<<dim3(DI_/256, B_, NCH_), 256, 0, stream>>>(
            xc, xpart, dbc, Alog_l, dtw_l, dtb_l, hL, sdt);
        k_scan_mid<<<(B_*DI_*DS_)/256, 256, 0, stream>>>(hL, sdt, Alog_l, hin);
        k_scan2<<<dim3(DI_/256, B_, NCH_), 256, 0, stream>>>(
            xc, dbc, Alog_l, dtw_l, dtb_l, hin, Dsk_l, xz, ygb);
        // out_proj + residual: x += ygb @ outwb^T
        k_mfma_nt<2, false><<<dim3(D_/128, BL_/128, 1), 256, 0, stream>>>(
            ygb, outwb_l, x, nullptr, D_, DI_, DI_, D_, DI_);
    }

    // final rmsnorm -> fp32
    k_rmsnorm<0><<<BL_, 192, 0, stream>>>(x, nfw, xn, nullptr);
    hipMemsetAsync(meanh, 0, (size_t)B_ * D_ * sizeof(float), stream);
    k_mean_partial<<<dim3(D_/256, B_, 16), 256, 0, stream>>>(xn, meanh);
    k_logits<<<1, 256, 0, stream>>>(meanh, clsw, clsb, out);
}